// Round 11
// baseline (91.622 us; speedup 1.0000x reference)
//
#include <hip/hip_runtime.h>
#include <cstddef>

typedef __attribute__((ext_vector_type(8))) __bf16 bf16x8;
typedef __attribute__((ext_vector_type(4))) float f32x4;
typedef unsigned short u16;
typedef unsigned int   u32;

#define SCLF (0.125f * 1.44269504f)   // softmax scale * log2(e), folded into q' weights

// ---------- helpers ----------
__device__ __forceinline__ u16 f2bf(float f){
  union { float f; u32 u; } v; v.f = f;
  u32 r = v.u + 0x7FFFu + ((v.u >> 16) & 1u);   // RNE
  return (u16)(r >> 16);
}
__device__ __forceinline__ u32 cvtpk(float lo, float hi){
  u32 r; asm("v_cvt_pk_bf16_f32 %0, %1, %2" : "=v"(r) : "v"(lo), "v"(hi)); return r;
}
__device__ __forceinline__ void gll16(const void* g, void* l){
  __builtin_amdgcn_global_load_lds((__attribute__((address_space(1))) void*)g,
                                   (__attribute__((address_space(3))) void*)l, 16, 0, 0);
}

// ---------- fold_qkv: Wt[1536][1024] bf16 (Bt layout), vectorized staging ----------
// part0: q' rows h*32+r = sum_d Wa[c][h*64+d]*ke[r][d]*SCLF
// part1: k_lat rows 512+h*32+r = sum_d Wa[c][1024+h*64+d]*kc[d][r]
// part2: v_lat rows 1024+h*32+r = sum_d Wa[c][2048+h*64+d]*vc[d][r]
__global__ __launch_bounds__(256) void fold_qkv(const float* __restrict__ Wa,
      const float* __restrict__ kc, const float* __restrict__ ke,
      const float* __restrict__ vc, u16* __restrict__ Wt){
  __shared__ float WaL[64*65];   // [c][d] stride 65 (bank c+d, 2-way free)
  __shared__ float Ws[2048];     // flat copy of M (native layout)
  const int bid = blockIdx.x;
  const int part = bid >> 8, rem = bid & 255, h = rem >> 4, cc = rem & 15;
  const int tid = threadIdx.x;
  {
    const float* msrc = (part==0) ? ke : (part==1) ? kc : vc;
    *(float4*)&Ws[tid*4]        = ((const float4*)msrc)[tid];
    *(float4*)&Ws[1024 + tid*4] = ((const float4*)msrc)[tid + 256];
  }
  const int c0 = cc*64, off = part*1024 + h*64;
  {
    int r0 = tid >> 4, c4 = (tid & 15) * 4;
    #pragma unroll
    for (int i=0;i<4;++i){
      int row = i*16 + r0;
      float4 v = *(const float4*)&Wa[(size_t)(c0+row)*3072 + off + c4];
      WaL[row*65 + c4 + 0] = v.x;
      WaL[row*65 + c4 + 1] = v.y;
      WaL[row*65 + c4 + 2] = v.z;
      WaL[row*65 + c4 + 3] = v.w;
    }
  }
  __syncthreads();
  const int c = tid & 63, rg = tid >> 6;      // wave-uniform rg -> Ws reads broadcast
  float acc[8] = {};
  if (part == 0){
    for (int d=0; d<64; ++d){
      float a = WaL[c*65 + d];
      #pragma unroll
      for (int rr=0;rr<8;++rr) acc[rr] += a * Ws[(rg*8+rr)*64 + d];   // ke[r][d]
    }
  } else {
    for (int d=0; d<64; ++d){
      float a = WaL[c*65 + d];
      #pragma unroll
      for (int rr=0;rr<8;++rr) acc[rr] += a * Ws[d*32 + rg*8 + rr];   // kc/vc[d][r]
    }
  }
  const float scl = (part==0) ? SCLF : 1.f;
  const int nbase = part*512 + h*32 + rg*8;
  #pragma unroll
  for (int rr=0;rr<8;++rr)
    Wt[(size_t)(nbase+rr)*1024 + c0 + c] = f2bf(acc[rr]*scl);
}

// ---------- fold_proj: W2t[j][h*32+r] = sum_d ve[r][d]*Wp[h*64+d][j], vectorized staging ----------
__global__ __launch_bounds__(256) void fold_proj(const float* __restrict__ Wp,
      const float* __restrict__ ve, u16* __restrict__ W2t){
  __shared__ float WpL[8192];   // [64 d][128 j]
  __shared__ float WeL[2048];   // [32 r][64 d] (native ve layout)
  const int jc = blockIdx.x, h = blockIdx.y;
  const int tid = threadIdx.x;
  {
    int dd = tid >> 5, c4 = (tid & 31) * 4;
    #pragma unroll
    for (int i=0;i<8;++i){
      int d = i*8 + dd;
      *(float4*)&WpL[d*128 + c4] = *(const float4*)&Wp[(size_t)(h*64+d)*1024 + jc*128 + c4];
    }
    *(float4*)&WeL[tid*4]        = ((const float4*)ve)[tid];
    *(float4*)&WeL[1024 + tid*4] = ((const float4*)ve)[tid + 256];
  }
  __syncthreads();
  const int jj = tid & 127, rg = tid >> 7;
  float out[16] = {};
  for (int d=0; d<64; ++d){
    float pv = WpL[d*128 + jj];
    #pragma unroll
    for (int rr=0; rr<16; ++rr) out[rr] += WeL[(rg*16+rr)*64 + d] * pv;
  }
  #pragma unroll
  for (int rr=0; rr<16; ++rr)
    W2t[(size_t)(jc*128 + jj)*512 + h*32 + rg*16 + rr] = f2bf(out[rr]);
}

// ---------- fold_bias: b2[1536], one block per part, LDS-staged padded M ----------
__global__ __launch_bounds__(256) void fold_bias(const float* __restrict__ ba,
      const float* __restrict__ kc, const float* __restrict__ ke,
      const float* __restrict__ vc, float* __restrict__ b2){
  __shared__ float BaL[1024];
  __shared__ float Ws65[32*65];   // [r][d] stride 65
  const int part = blockIdx.x, tid = threadIdx.x;
  *(float4*)&BaL[tid*4] = *(const float4*)&ba[part*1024 + tid*4];
  {
    const float* msrc = (part==0) ? ke : (part==1) ? kc : vc;
    #pragma unroll
    for (int i=0;i<8;++i){
      int idx = tid + i*256;
      float v = msrc[idx];
      int r, d;
      if (part == 0){ r = idx >> 6; d = idx & 63; }      // ke[r][d]
      else          { d = idx >> 5; r = idx & 31; }      // kc/vc[d][r]
      Ws65[r*65 + d] = v;
    }
  }
  __syncthreads();
  const float scl = (part==0) ? SCLF : 1.f;
  #pragma unroll
  for (int t=0;t<2;++t){
    int l = tid + t*256;            // local output in [0,512)
    int hh = l >> 5, r = l & 31;
    float acc = 0.f;
    for (int d=0;d<64;++d) acc += BaL[hh*64 + d] * Ws65[r*65 + d];
    b2[part*512 + l] = acc * scl;
  }
}

// ---------- V transpose (latent): QKV' v_lat part -> Vt[bh*32+r][t], k-slot-permuted ----------
__global__ __launch_bounds__(256) void v_transpose_lat(const u16* __restrict__ QKV,
      u16* __restrict__ Vt){
  __shared__ u16 tile[64][40];   // [t][r] padded
  int tt = blockIdx.x, bh = blockIdx.y;
  int b = bh>>4, h = bh&15;
  int tid = threadIdx.x;
  int row = tid>>2, cc2 = (tid&3)*8;
  const u16* src = QKV + (size_t)(b*2048 + tt*64 + row)*1536 + 1024 + h*32 + cc2;
  *(uint4*)&tile[row][cc2] = *(const uint4*)src;
  __syncthreads();
  int r = tid>>3, pc = (tid&7)*8;
  u16 vals[8];
  #pragma unroll
  for (int i=0;i<8;++i){
    int p = pc+i; int c = p>>5, q = p&31, g = q>>3, j = q&7;
    int o = c*32 + 16*(j>>2) + 4*g + (j&3);
    vals[i] = tile[o][r];
  }
  u16* drow = Vt + (size_t)(bh*32 + r)*2048 + tt*64 + pc;
  *(uint4*)drow = *(const uint4*)&vals[0];
}

// ---------- 64x128 bf16 GEMM (2-phase): C[M,N] = A[M,K]*Bt[N,K]^T + bias ----------
// AT=float: A is raw f32, converted to bf16 during register staging (RNE == f2bf).
// AT=u16:   A staged via global_load_lds (original path).
template<typename AT, typename OT>
__global__ __launch_bounds__(256) void gemm64(const AT* __restrict__ A, const u16* __restrict__ Bt,
        const float* __restrict__ bias, OT* __restrict__ C, int M, int N, int K, int ldc){
  __shared__ u16 As[64*64];     // 8 chunks
  __shared__ u16 Bs[128*64];    // 16 chunks
  const int nwg = gridDim.x * gridDim.y;
  const int id  = blockIdx.x + gridDim.x * blockIdx.y;
  const int nid = (id & 7) * (nwg >> 3) + (id >> 3);   // nwg % 8 == 0
  const int bx = nid % gridDim.x, by = nid / gridDim.x;
  const int tid = threadIdx.x, wv = tid>>6, ln = tid&63;
  const int lr = ln&15, g8 = (ln>>4)*8;
  const int m0 = bx*64, n0 = by*128;
  const int wr = (wv>>1)*32, wc = (wv&1)*64;
  const int lrow = ln>>3, lcol = (ln&7)*8;
  f32x4 acc[2][4] = {};
  const int nk = K >> 6;
  for (int kt=0; kt<nk; ++kt){
    if constexpr (sizeof(AT) == 4){
      // reg-stage A from f32 with inline bf16 conversion
      int row = tid>>2, seg = (tid&3)*16;
      const float* xs = (const float*)A + (size_t)(m0+row)*K + kt*64 + seg;
      float4 a0 = ((const float4*)xs)[0], a1 = ((const float4*)xs)[1],
             a2 = ((const float4*)xs)[2], a3 = ((const float4*)xs)[3];
      uint4 w0, w1;
      w0.x = cvtpk(a0.x,a0.y); w0.y = cvtpk(a0.z,a0.w);
      w0.z = cvtpk(a1.x,a1.y); w0.w = cvtpk(a1.z,a1.w);
      w1.x = cvtpk(a2.x,a2.y); w1.y = cvtpk(a2.z,a2.w);
      w1.z = cvtpk(a3.x,a3.y); w1.w = cvtpk(a3.z,a3.w);
      *(uint4*)&As[row*64 + seg]     = w0;
      *(uint4*)&As[row*64 + seg + 8] = w1;
      #pragma unroll
      for (int it=0; it<4; ++it){
        int bc = wv*4 + it;
        int rowb = bc*8 + lrow;
        gll16(Bt + (size_t)(n0+rowb)*K + kt*64 + lcol, &Bs[bc*512]);
      }
    } else {
      #pragma unroll
      for (int it=0; it<6; ++it){
        int chunk = wv*6 + it;                  // 0..23: first 8 A, rest B
        if (chunk < 8){
          int row = chunk*8 + lrow;
          gll16((const u16*)A + (size_t)(m0+row)*K + kt*64 + lcol, &As[chunk*512]);
        } else {
          int bc = chunk - 8;
          int row = bc*8 + lrow;
          gll16(Bt + (size_t)(n0+row)*K + kt*64 + lcol, &Bs[bc*512]);
        }
      }
    }
    __syncthreads();
    #pragma unroll
    for (int ks=0; ks<2; ++ks){
      bf16x8 af[2], bfr[4];
      #pragma unroll
      for (int mt=0;mt<2;++mt) af[mt]  = *(const bf16x8*)&As[(wr+mt*16+lr)*64 + ks*32 + g8];
      #pragma unroll
      for (int nt=0;nt<4;++nt) bfr[nt] = *(const bf16x8*)&Bs[(wc+nt*16+lr)*64 + ks*32 + g8];
      #pragma unroll
      for (int mt=0;mt<2;++mt)
        #pragma unroll
        for (int nt=0;nt<4;++nt)
          acc[mt][nt] = __builtin_amdgcn_mfma_f32_16x16x32_bf16(af[mt], bfr[nt], acc[mt][nt], 0,0,0);
    }
    __syncthreads();
  }
  #pragma unroll
  for (int mt=0;mt<2;++mt){
    int row = m0 + wr + mt*16 + 4*(ln>>4);
    #pragma unroll
    for (int nt=0;nt<4;++nt){
      int col = n0 + wc + nt*16 + lr;
      float bv = bias[col];
      #pragma unroll
      for (int r=0;r<4;++r){
        float v = acc[mt][nt][r] + bv;
        if constexpr (sizeof(OT) == 2) C[(size_t)(row+r)*ldc + col] = f2bf(v);
        else                           C[(size_t)(row+r)*ldc + col] = v;
      }
    }
  }
}

// ---------- causal flash attention in rank-32 latent space ----------
// QKV'[4096][1536]: q' (SCLF-scaled) at 0, k_lat at 512, v_lat at 1024 (+h*32).
// Vt[bh*32+r][2048] permuted. Out = Att[4096][512]. No-max softmax (bounded scores).
// grid (bh=32, y=32) qt=31-y (LPT); 512 thr = 2 subgroups x 4 waves, kt ≡ sg (mod 2).
__global__ __launch_bounds__(512, 8) void attn_fwd(const u16* __restrict__ QKV,
            const u16* __restrict__ Vt, u16* __restrict__ Out){
  const int bh = blockIdx.x;
  const int qt = 31 - blockIdx.y;
  const int b = bh >> 4, h = bh & 15;
  const int tid = threadIdx.x, wv = tid>>6, ln = tid&63;
  const int sg = wv>>2, wvL = wv&3;
  const int lr = ln&15, gq = ln>>4;
  __shared__ __align__(16) char SMEM[32768];
  u16* KB0 = (u16*)SMEM           + (sg*2    )*2048;   // 4 KB tiles [64 kv][32 d]
  u16* KB1 = (u16*)SMEM           + (sg*2 + 1)*2048;
  u16* VB0 = (u16*)(SMEM + 16384) + (sg*2    )*2048;   // 4 KB tiles [32 r][64 kv-perm]
  u16* VB1 = (u16*)(SMEM + 16384) + (sg*2 + 1)*2048;
  const int q0 = qt*64;
  const size_t base = (size_t)(b*2048) * 1536;
  bf16x8 qf = *(const bf16x8*)(QKV + base + (size_t)(q0 + wvL*16 + lr)*1536 + h*32 + gq*8);
  const int qglob = q0 + wvL*16 + lr;
  f32x4 o0 = {}, o1 = {};
  float l_r = 0.f;
  const u16* ksrc = QKV + base + 512 + h*32;
  const u16* vsrc = Vt + (size_t)(bh*32)*2048;

  const int ci = wvL*64 + ln;
  const int rK = ci>>2, cK = 8*((ci&3) ^ (rK&3));      // K row 64B: swz bits[5:4]
  const int rV = ci>>3, cV = 8*((ci&7) ^ (rV&7));      // V row 128B: swz bits[6:4]

  int offK[4], offV[2][2];
  #pragma unroll
  for (int nt=0;nt<4;++nt)
    offK[nt] = (nt*16+lr)*64 + ((gq*16) ^ ((lr&3)<<4));
  #pragma unroll
  for (int dt=0;dt<2;++dt)
    #pragma unroll
    for (int c=0;c<2;++c)
      offV[dt][c] = (dt*16+lr)*128 + ((c*64 + gq*16) ^ ((lr&7)<<4));

  if (sg <= qt){
    gll16(ksrc + (size_t)(sg*64 + rK)*1536 + cK, KB0 + wvL*512);
    gll16(vsrc + (size_t)rV*2048 + sg*64 + cV,   VB0 + wvL*512);
  }
  __syncthreads();
  const u16* kp = ksrc + (size_t)(sg*64 + 128 + rK)*1536 + cK;
  const u16* vp = vsrc + (size_t)rV*2048 + sg*64 + 128 + cV;
  const size_t KSTEP = (size_t)128*1536;

  #define ABODY(II, KBC, VBC, KBN, VBN) do { \
    const int kt = 2*(II) + sg; \
    if (kt + 2 <= qt){ \
      gll16(kp, (KBN) + wvL*512); \
      gll16(vp, (VBN) + wvL*512); \
      kp += KSTEP; vp += 128; \
    } \
    if (kt <= qt){ \
      f32x4 s4[4] = {}; \
      __builtin_amdgcn_s_setprio(1); \
      _Pragma("unroll") for (int nt=0;nt<4;++nt){ \
        bf16x8 k0 = *(const bf16x8*)((const char*)(KBC) + offK[nt]); \
        s4[nt] = __builtin_amdgcn_mfma_f32_16x16x32_bf16(k0, qf, s4[nt], 0,0,0); \
      } \
      __builtin_amdgcn_s_setprio(0); \
      if (kt == qt){ \
        const int kv0 = kt*64; \
        _Pragma("unroll") for (int nt=0;nt<4;++nt) \
        _Pragma("unroll") for (int r=0;r<4;++r){ \
          int k = kv0 + nt*16 + 4*gq + r; \
          if (k > qglob) s4[nt][r] = -1e30f; \
        } \
      } \
      float p0,p1,p2,p3,p4,p5,p6,p7; \
      p0=__builtin_amdgcn_exp2f(s4[0][0]); p1=__builtin_amdgcn_exp2f(s4[0][1]); \
      p2=__builtin_amdgcn_exp2f(s4[0][2]); p3=__builtin_amdgcn_exp2f(s4[0][3]); \
      p4=__builtin_amdgcn_exp2f(s4[1][0]); p5=__builtin_amdgcn_exp2f(s4[1][1]); \
      p6=__builtin_amdgcn_exp2f(s4[1][2]); p7=__builtin_amdgcn_exp2f(s4[1][3]); \
      l_r += ((p0+p1)+(p2+p3)) + ((p4+p5)+(p6+p7)); \
      union { u32 u[4]; bf16x8 v; } pa0, pa1; \
      pa0.u[0]=cvtpk(p0,p1); pa0.u[1]=cvtpk(p2,p3); pa0.u[2]=cvtpk(p4,p5); pa0.u[3]=cvtpk(p6,p7); \
      p0=__builtin_amdgcn_exp2f(s4[2][0]); p1=__builtin_amdgcn_exp2f(s4[2][1]); \
      p2=__builtin_amdgcn_exp2f(s4[2][2]); p3=__builtin_amdgcn_exp2f(s4[2][3]); \
      p4=__builtin_amdgcn_exp2f(s4[3][0]); p5=__builtin_amdgcn_exp2f(s4[3][1]); \
      p6=__builtin_amdgcn_exp2f(s4[3][2]); p7=__builtin_amdgcn_exp2f(s4[3][3]); \
      l_r += ((p0+p1)+(p2+p3)) + ((p4+p5)+(p6+p7)); \
      pa1.u[0]=cvtpk(p0,p1); pa1.u[1]=cvtpk(p2,p3); pa1.u[2]=cvtpk(p4,p5); pa1.u[3]=cvtpk(p6,p7); \
      __builtin_amdgcn_s_setprio(1); \
      o0 = __builtin_amdgcn_mfma_f32_16x16x32_bf16(pa0.v, *(const bf16x8*)((const char*)(VBC) + offV[0][0]), o0, 0,0,0); \
      o1 = __builtin_amdgcn_mfma_f32_16x16x32_bf16(pa0.v, *(const bf16x8*)((const char*)(VBC) + offV[1][0]), o1, 0,0,0); \
      o0 = __builtin_amdgcn_mfma_f32_16x16x32_bf16(pa1.v, *(const bf16x8*)((const char*)(VBC) + offV[0][1]), o0, 0,0,0); \
      o1 = __builtin_amdgcn_mfma_f32_16x16x32_bf16(pa1.v, *(const bf16x8*)((const char*)(VBC) + offV[1][1]), o1, 0,0,0); \
      __builtin_amdgcn_s_setprio(0); \
    } \
    __syncthreads(); \
  } while(0)

  const int nmax = (qt + 2) >> 1;
  const int jmax = (nmax + 1) >> 1;
  for (int j = 0; j < jmax; ++j){
    ABODY(2*j,   KB0, VB0, KB1, VB1);
    ABODY(2*j+1, KB1, VB1, KB0, VB0);
  }
  l_r += __shfl_xor(l_r, 16);
  l_r += __shfl_xor(l_r, 32);

  // ---- in-LDS merge of the two partial (unnormalized) results ----
  float* MO = (float*)SMEM;               // [64][34] padded
  float* ML = (float*)(SMEM + 12288);     // l[64]
  if (sg == 1){
    #pragma unroll
    for (int r=0;r<4;++r){
      MO[(wvL*16 + 4*gq + r)*34 + lr]      = o0[r];
      MO[(wvL*16 + 4*gq + r)*34 + 16 + lr] = o1[r];
    }
    if (gq == 0) ML[wvL*16 + lr] = l_r;
  }
  __syncthreads();
  if (sg == 0){
    float lS = l_r + ML[wvL*16 + lr];
    float lS_o[4];
    #pragma unroll
    for (int r=0;r<4;++r) lS_o[r] = __shfl(lS, 4*gq + r);
    #pragma unroll
    for (int r=0;r<4;++r){
      int orow = wvL*16 + 4*gq + r;
      float v0 = (o0[r] + MO[orow*34 + lr])      / lS_o[r];
      float v1 = (o1[r] + MO[orow*34 + 16 + lr]) / lS_o[r];
      size_t ob = (size_t)(b*2048 + q0 + orow)*512 + h*32;
      Out[ob + lr]      = f2bf(v0);
      Out[ob + 16 + lr] = f2bf(v1);
    }
  }
}

// ---------- workspace layout (bytes) ----------
#define WS_B2   0u
#define WS_WT   8192u                                // 1536*1024*2 = 3145728
#define WS_W2T  (WS_WT + 3145728u)                   // 1024*512*2  = 1048576
#define WS_QKV  (WS_W2T + 1048576u)                  // 4096*1536*2 = 12582912
#define WS_VT   (WS_QKV + 12582912u)                 // 1024*2048*2 = 4194304
#define WS_ATT  (WS_VT + 4194304u)                   // 4096*512*2  = 4194304

extern "C" void kernel_launch(void* const* d_in, const int* in_sizes, int n_in,
                              void* d_out, int out_size, void* d_ws, size_t ws_size,
                              hipStream_t stream) {
  const float* x  = (const float*)d_in[0];
  const float* Wa = (const float*)d_in[1];
  const float* ba = (const float*)d_in[2];
  const float* Wp = (const float*)d_in[3];
  const float* bp = (const float*)d_in[4];
  const float* kc = (const float*)d_in[5];
  const float* ke = (const float*)d_in[6];
  const float* vc = (const float*)d_in[7];
  const float* ve = (const float*)d_in[8];
  float* out = (float*)d_out;
  char* ws = (char*)d_ws;
  float* b2  = (float*)(ws + WS_B2);
  u16* Wt    = (u16*)(ws + WS_WT);
  u16* W2t   = (u16*)(ws + WS_W2T);
  u16* QKVb  = (u16*)(ws + WS_QKV);
  u16* Vt    = (u16*)(ws + WS_VT);
  u16* Att   = (u16*)(ws + WS_ATT);

  fold_bias<<<3, 256, 0, stream>>>(ba, kc, ke, vc, b2);
  fold_proj<<<dim3(8,16), 256, 0, stream>>>(Wp, ve, W2t);
  fold_qkv<<<768, 256, 0, stream>>>(Wa, kc, ke, vc, Wt);
  gemm64<float,u16><<<dim3(64,12), 256, 0, stream>>>(x, Wt, b2, QKVb, 4096, 1536, 1024, 1536);
  v_transpose_lat<<<dim3(32,32), 256, 0, stream>>>(QKVb, Vt);
  attn_fwd<<<dim3(32,32), 512, 0, stream>>>(QKVb, Vt, Att);
  gemm64<u16,float><<<dim3(64,8), 256, 0, stream>>>(Att, W2t, bp, out, 4096, 1024, 512, 1024);
}

// Round 12
// 90.093 us; speedup vs baseline: 1.0170x; 1.0170x over previous
//
#include <hip/hip_runtime.h>
#include <cstddef>

typedef __attribute__((ext_vector_type(8))) __bf16 bf16x8;
typedef __attribute__((ext_vector_type(4))) float f32x4;
typedef unsigned short u16;
typedef unsigned int   u32;

#define SCLF (0.125f * 1.44269504f)   // softmax scale * log2(e), folded into q' weights

// ---------- helpers ----------
__device__ __forceinline__ u16 f2bf(float f){
  union { float f; u32 u; } v; v.f = f;
  u32 r = v.u + 0x7FFFu + ((v.u >> 16) & 1u);   // RNE
  return (u16)(r >> 16);
}
__device__ __forceinline__ u32 cvtpk(float lo, float hi){
  u32 r; asm("v_cvt_pk_bf16_f32 %0, %1, %2" : "=v"(r) : "v"(lo), "v"(hi)); return r;
}
__device__ __forceinline__ void gll16(const void* g, void* l){
  __builtin_amdgcn_global_load_lds((__attribute__((address_space(1))) void*)g,
                                   (__attribute__((address_space(3))) void*)l, 16, 0, 0);
}

// ---------- prep: x fp32 -> bf16 (vectorized) ----------
__global__ void convert_x(const float* __restrict__ x, u16* __restrict__ o, int n4){
  int i = blockIdx.x*blockDim.x + threadIdx.x;
  if (i >= n4) return;
  float4 v = ((const float4*)x)[i];
  ushort4 r; r.x = f2bf(v.x); r.y = f2bf(v.y); r.z = f2bf(v.z); r.w = f2bf(v.w);
  ((ushort4*)o)[i] = r;
}

// ---------- fold_qkv: Wt[1536][1024] bf16 (Bt layout), vectorized staging ----------
__global__ __launch_bounds__(256) void fold_qkv(const float* __restrict__ Wa,
      const float* __restrict__ kc, const float* __restrict__ ke,
      const float* __restrict__ vc, u16* __restrict__ Wt){
  __shared__ float WaL[64*65];   // [c][d] stride 65 (bank c+d, 2-way free)
  __shared__ float Ws[2048];     // flat copy of M (native layout)
  const int bid = blockIdx.x;
  const int part = bid >> 8, rem = bid & 255, h = rem >> 4, cc = rem & 15;
  const int tid = threadIdx.x;
  {
    const float* msrc = (part==0) ? ke : (part==1) ? kc : vc;
    *(float4*)&Ws[tid*4]        = ((const float4*)msrc)[tid];
    *(float4*)&Ws[1024 + tid*4] = ((const float4*)msrc)[tid + 256];
  }
  const int c0 = cc*64, off = part*1024 + h*64;
  {
    int r0 = tid >> 4, c4 = (tid & 15) * 4;
    #pragma unroll
    for (int i=0;i<4;++i){
      int row = i*16 + r0;
      float4 v = *(const float4*)&Wa[(size_t)(c0+row)*3072 + off + c4];
      WaL[row*65 + c4 + 0] = v.x;
      WaL[row*65 + c4 + 1] = v.y;
      WaL[row*65 + c4 + 2] = v.z;
      WaL[row*65 + c4 + 3] = v.w;
    }
  }
  __syncthreads();
  const int c = tid & 63, rg = tid >> 6;      // wave-uniform rg -> Ws reads broadcast
  float acc[8] = {};
  if (part == 0){
    for (int d=0; d<64; ++d){
      float a = WaL[c*65 + d];
      #pragma unroll
      for (int rr=0;rr<8;++rr) acc[rr] += a * Ws[(rg*8+rr)*64 + d];   // ke[r][d]
    }
  } else {
    for (int d=0; d<64; ++d){
      float a = WaL[c*65 + d];
      #pragma unroll
      for (int rr=0;rr<8;++rr) acc[rr] += a * Ws[d*32 + rg*8 + rr];   // kc/vc[d][r]
    }
  }
  const float scl = (part==0) ? SCLF : 1.f;
  const int nbase = part*512 + h*32 + rg*8;
  #pragma unroll
  for (int rr=0;rr<8;++rr)
    Wt[(size_t)(nbase+rr)*1024 + c0 + c] = f2bf(acc[rr]*scl);
}

// ---------- fold_proj: W2t[j][h*32+r] = sum_d ve[r][d]*Wp[h*64+d][j], vectorized staging ----------
__global__ __launch_bounds__(256) void fold_proj(const float* __restrict__ Wp,
      const float* __restrict__ ve, u16* __restrict__ W2t){
  __shared__ float WpL[8192];   // [64 d][128 j]
  __shared__ float WeL[2048];   // [32 r][64 d] (native ve layout)
  const int jc = blockIdx.x, h = blockIdx.y;
  const int tid = threadIdx.x;
  {
    int dd = tid >> 5, c4 = (tid & 31) * 4;
    #pragma unroll
    for (int i=0;i<8;++i){
      int d = i*8 + dd;
      *(float4*)&WpL[d*128 + c4] = *(const float4*)&Wp[(size_t)(h*64+d)*1024 + jc*128 + c4];
    }
    *(float4*)&WeL[tid*4]        = ((const float4*)ve)[tid];
    *(float4*)&WeL[1024 + tid*4] = ((const float4*)ve)[tid + 256];
  }
  __syncthreads();
  const int jj = tid & 127, rg = tid >> 7;
  float out[16] = {};
  for (int d=0; d<64; ++d){
    float pv = WpL[d*128 + jj];
    #pragma unroll
    for (int rr=0; rr<16; ++rr) out[rr] += WeL[(rg*16+rr)*64 + d] * pv;
  }
  #pragma unroll
  for (int rr=0; rr<16; ++rr)
    W2t[(size_t)(jc*128 + jj)*512 + h*32 + rg*16 + rr] = f2bf(out[rr]);
}

// ---------- fold_bias: b2[1536], one block per part, LDS-staged padded M ----------
__global__ __launch_bounds__(256) void fold_bias(const float* __restrict__ ba,
      const float* __restrict__ kc, const float* __restrict__ ke,
      const float* __restrict__ vc, float* __restrict__ b2){
  __shared__ float BaL[1024];
  __shared__ float Ws65[32*65];   // [r][d] stride 65
  const int part = blockIdx.x, tid = threadIdx.x;
  *(float4*)&BaL[tid*4] = *(const float4*)&ba[part*1024 + tid*4];
  {
    const float* msrc = (part==0) ? ke : (part==1) ? kc : vc;
    #pragma unroll
    for (int i=0;i<8;++i){
      int idx = tid + i*256;
      float v = msrc[idx];
      int r, d;
      if (part == 0){ r = idx >> 6; d = idx & 63; }      // ke[r][d]
      else          { d = idx >> 5; r = idx & 31; }      // kc/vc[d][r]
      Ws65[r*65 + d] = v;
    }
  }
  __syncthreads();
  const float scl = (part==0) ? SCLF : 1.f;
  #pragma unroll
  for (int t=0;t<2;++t){
    int l = tid + t*256;            // local output in [0,512)
    int hh = l >> 5, r = l & 31;
    float acc = 0.f;
    for (int d=0;d<64;++d) acc += BaL[hh*64 + d] * Ws65[r*65 + d];
    b2[part*512 + l] = acc * scl;
  }
}

// ---------- V transpose (latent): QKV' v_lat part -> Vt[bh*32+r][t], k-slot-permuted ----------
__global__ __launch_bounds__(256) void v_transpose_lat(const u16* __restrict__ QKV,
      u16* __restrict__ Vt){
  __shared__ u16 tile[64][40];   // [t][r] padded
  int tt = blockIdx.x, bh = blockIdx.y;
  int b = bh>>4, h = bh&15;
  int tid = threadIdx.x;
  int row = tid>>2, cc2 = (tid&3)*8;
  const u16* src = QKV + (size_t)(b*2048 + tt*64 + row)*1536 + 1024 + h*32 + cc2;
  *(uint4*)&tile[row][cc2] = *(const uint4*)src;
  __syncthreads();
  int r = tid>>3, pc = (tid&7)*8;
  u16 vals[8];
  #pragma unroll
  for (int i=0;i<8;++i){
    int p = pc+i; int c = p>>5, q = p&31, g = q>>3, j = q&7;
    int o = c*32 + 16*(j>>2) + 4*g + (j&3);
    vals[i] = tile[o][r];
  }
  u16* drow = Vt + (size_t)(bh*32 + r)*2048 + tt*64 + pc;
  *(uint4*)drow = *(const uint4*)&vals[0];
}

// ---------- 64x128 bf16 GEMM (2-phase, gll16 both operands): C = A*Bt^T + bias ----------
template<typename OT>
__global__ __launch_bounds__(256) void gemm64(const u16* __restrict__ A, const u16* __restrict__ Bt,
        const float* __restrict__ bias, OT* __restrict__ C, int M, int N, int K, int ldc){
  __shared__ u16 As[64*64];     // 8 chunks
  __shared__ u16 Bs[128*64];    // 16 chunks
  const int nwg = gridDim.x * gridDim.y;
  const int id  = blockIdx.x + gridDim.x * blockIdx.y;
  const int nid = (id & 7) * (nwg >> 3) + (id >> 3);   // nwg % 8 == 0
  const int bx = nid % gridDim.x, by = nid / gridDim.x;
  const int tid = threadIdx.x, wv = tid>>6, ln = tid&63;
  const int lr = ln&15, g8 = (ln>>4)*8;
  const int m0 = bx*64, n0 = by*128;
  const int wr = (wv>>1)*32, wc = (wv&1)*64;
  const int lrow = ln>>3, lcol = (ln&7)*8;
  f32x4 acc[2][4] = {};
  const int nk = K >> 6;
  for (int kt=0; kt<nk; ++kt){
    #pragma unroll
    for (int it=0; it<6; ++it){
      int chunk = wv*6 + it;                  // 0..23: first 8 A, rest B
      if (chunk < 8){
        int row = chunk*8 + lrow;
        gll16(A + (size_t)(m0+row)*K + kt*64 + lcol, &As[chunk*512]);
      } else {
        int bc = chunk - 8;
        int row = bc*8 + lrow;
        gll16(Bt + (size_t)(n0+row)*K + kt*64 + lcol, &Bs[bc*512]);
      }
    }
    __syncthreads();
    #pragma unroll
    for (int ks=0; ks<2; ++ks){
      bf16x8 af[2], bfr[4];
      #pragma unroll
      for (int mt=0;mt<2;++mt) af[mt]  = *(const bf16x8*)&As[(wr+mt*16+lr)*64 + ks*32 + g8];
      #pragma unroll
      for (int nt=0;nt<4;++nt) bfr[nt] = *(const bf16x8*)&Bs[(wc+nt*16+lr)*64 + ks*32 + g8];
      #pragma unroll
      for (int mt=0;mt<2;++mt)
        #pragma unroll
        for (int nt=0;nt<4;++nt)
          acc[mt][nt] = __builtin_amdgcn_mfma_f32_16x16x32_bf16(af[mt], bfr[nt], acc[mt][nt], 0,0,0);
    }
    __syncthreads();
  }
  #pragma unroll
  for (int mt=0;mt<2;++mt){
    int row = m0 + wr + mt*16 + 4*(ln>>4);
    #pragma unroll
    for (int nt=0;nt<4;++nt){
      int col = n0 + wc + nt*16 + lr;
      float bv = bias[col];
      #pragma unroll
      for (int r=0;r<4;++r){
        float v = acc[mt][nt][r] + bv;
        if constexpr (sizeof(OT) == 2) C[(size_t)(row+r)*ldc + col] = f2bf(v);
        else                           C[(size_t)(row+r)*ldc + col] = v;
      }
    }
  }
}

// ---------- causal flash attention in rank-32 latent space ----------
// QKV'[4096][1536]: q' (SCLF-scaled) at 0, k_lat at 512, v_lat at 1024 (+h*32).
// Vt[bh*32+r][2048] permuted. Out = Att[4096][512]. No-max softmax (bounded scores).
// grid (bh=32, y=32) qt=31-y (LPT); 512 thr = 2 subgroups x 4 waves, kt ≡ sg (mod 2).
__global__ __launch_bounds__(512, 8) void attn_fwd(const u16* __restrict__ QKV,
            const u16* __restrict__ Vt, u16* __restrict__ Out){
  const int bh = blockIdx.x;
  const int qt = 31 - blockIdx.y;
  const int b = bh >> 4, h = bh & 15;
  const int tid = threadIdx.x, wv = tid>>6, ln = tid&63;
  const int sg = wv>>2, wvL = wv&3;
  const int lr = ln&15, gq = ln>>4;
  __shared__ __align__(16) char SMEM[32768];
  u16* KB0 = (u16*)SMEM           + (sg*2    )*2048;   // 4 KB tiles [64 kv][32 d]
  u16* KB1 = (u16*)SMEM           + (sg*2 + 1)*2048;
  u16* VB0 = (u16*)(SMEM + 16384) + (sg*2    )*2048;   // 4 KB tiles [32 r][64 kv-perm]
  u16* VB1 = (u16*)(SMEM + 16384) + (sg*2 + 1)*2048;
  const int q0 = qt*64;
  const size_t base = (size_t)(b*2048) * 1536;
  bf16x8 qf = *(const bf16x8*)(QKV + base + (size_t)(q0 + wvL*16 + lr)*1536 + h*32 + gq*8);
  const int qglob = q0 + wvL*16 + lr;
  f32x4 o0 = {}, o1 = {};
  float l_r = 0.f;
  const u16* ksrc = QKV + base + 512 + h*32;
  const u16* vsrc = Vt + (size_t)(bh*32)*2048;

  const int ci = wvL*64 + ln;
  const int rK = ci>>2, cK = 8*((ci&3) ^ (rK&3));      // K row 64B: swz bits[5:4]
  const int rV = ci>>3, cV = 8*((ci&7) ^ (rV&7));      // V row 128B: swz bits[6:4]

  int offK[4], offV[2][2];
  #pragma unroll
  for (int nt=0;nt<4;++nt)
    offK[nt] = (nt*16+lr)*64 + ((gq*16) ^ ((lr&3)<<4));
  #pragma unroll
  for (int dt=0;dt<2;++dt)
    #pragma unroll
    for (int c=0;c<2;++c)
      offV[dt][c] = (dt*16+lr)*128 + ((c*64 + gq*16) ^ ((lr&7)<<4));

  if (sg <= qt){
    gll16(ksrc + (size_t)(sg*64 + rK)*1536 + cK, KB0 + wvL*512);
    gll16(vsrc + (size_t)rV*2048 + sg*64 + cV,   VB0 + wvL*512);
  }
  __syncthreads();
  const u16* kp = ksrc + (size_t)(sg*64 + 128 + rK)*1536 + cK;
  const u16* vp = vsrc + (size_t)rV*2048 + sg*64 + 128 + cV;
  const size_t KSTEP = (size_t)128*1536;

  #define ABODY(II, KBC, VBC, KBN, VBN) do { \
    const int kt = 2*(II) + sg; \
    if (kt + 2 <= qt){ \
      gll16(kp, (KBN) + wvL*512); \
      gll16(vp, (VBN) + wvL*512); \
      kp += KSTEP; vp += 128; \
    } \
    if (kt <= qt){ \
      f32x4 s4[4] = {}; \
      __builtin_amdgcn_s_setprio(1); \
      _Pragma("unroll") for (int nt=0;nt<4;++nt){ \
        bf16x8 k0 = *(const bf16x8*)((const char*)(KBC) + offK[nt]); \
        s4[nt] = __builtin_amdgcn_mfma_f32_16x16x32_bf16(k0, qf, s4[nt], 0,0,0); \
      } \
      __builtin_amdgcn_s_setprio(0); \
      if (kt == qt){ \
        const int kv0 = kt*64; \
        _Pragma("unroll") for (int nt=0;nt<4;++nt) \
        _Pragma("unroll") for (int r=0;r<4;++r){ \
          int k = kv0 + nt*16 + 4*gq + r; \
          if (k > qglob) s4[nt][r] = -1e30f; \
        } \
      } \
      float p0,p1,p2,p3,p4,p5,p6,p7; \
      p0=__builtin_amdgcn_exp2f(s4[0][0]); p1=__builtin_amdgcn_exp2f(s4[0][1]); \
      p2=__builtin_amdgcn_exp2f(s4[0][2]); p3=__builtin_amdgcn_exp2f(s4[0][3]); \
      p4=__builtin_amdgcn_exp2f(s4[1][0]); p5=__builtin_amdgcn_exp2f(s4[1][1]); \
      p6=__builtin_amdgcn_exp2f(s4[1][2]); p7=__builtin_amdgcn_exp2f(s4[1][3]); \
      l_r += ((p0+p1)+(p2+p3)) + ((p4+p5)+(p6+p7)); \
      union { u32 u[4]; bf16x8 v; } pa0, pa1; \
      pa0.u[0]=cvtpk(p0,p1); pa0.u[1]=cvtpk(p2,p3); pa0.u[2]=cvtpk(p4,p5); pa0.u[3]=cvtpk(p6,p7); \
      p0=__builtin_amdgcn_exp2f(s4[2][0]); p1=__builtin_amdgcn_exp2f(s4[2][1]); \
      p2=__builtin_amdgcn_exp2f(s4[2][2]); p3=__builtin_amdgcn_exp2f(s4[2][3]); \
      p4=__builtin_amdgcn_exp2f(s4[3][0]); p5=__builtin_amdgcn_exp2f(s4[3][1]); \
      p6=__builtin_amdgcn_exp2f(s4[3][2]); p7=__builtin_amdgcn_exp2f(s4[3][3]); \
      l_r += ((p0+p1)+(p2+p3)) + ((p4+p5)+(p6+p7)); \
      pa1.u[0]=cvtpk(p0,p1); pa1.u[1]=cvtpk(p2,p3); pa1.u[2]=cvtpk(p4,p5); pa1.u[3]=cvtpk(p6,p7); \
      __builtin_amdgcn_s_setprio(1); \
      o0 = __builtin_amdgcn_mfma_f32_16x16x32_bf16(pa0.v, *(const bf16x8*)((const char*)(VBC) + offV[0][0]), o0, 0,0,0); \
      o1 = __builtin_amdgcn_mfma_f32_16x16x32_bf16(pa0.v, *(const bf16x8*)((const char*)(VBC) + offV[1][0]), o1, 0,0,0); \
      o0 = __builtin_amdgcn_mfma_f32_16x16x32_bf16(pa1.v, *(const bf16x8*)((const char*)(VBC) + offV[0][1]), o0, 0,0,0); \
      o1 = __builtin_amdgcn_mfma_f32_16x16x32_bf16(pa1.v, *(const bf16x8*)((const char*)(VBC) + offV[1][1]), o1, 0,0,0); \
      __builtin_amdgcn_s_setprio(0); \
    } \
    __syncthreads(); \
  } while(0)

  const int nmax = (qt + 2) >> 1;
  const int jmax = (nmax + 1) >> 1;
  for (int j = 0; j < jmax; ++j){
    ABODY(2*j,   KB0, VB0, KB1, VB1);
    ABODY(2*j+1, KB1, VB1, KB0, VB0);
  }
  l_r += __shfl_xor(l_r, 16);
  l_r += __shfl_xor(l_r, 32);

  // ---- in-LDS merge of the two partial (unnormalized) results ----
  float* MO = (float*)SMEM;               // [64][34] padded
  float* ML = (float*)(SMEM + 12288);     // l[64]
  if (sg == 1){
    #pragma unroll
    for (int r=0;r<4;++r){
      MO[(wvL*16 + 4*gq + r)*34 + lr]      = o0[r];
      MO[(wvL*16 + 4*gq + r)*34 + 16 + lr] = o1[r];
    }
    if (gq == 0) ML[wvL*16 + lr] = l_r;
  }
  __syncthreads();
  if (sg == 0){
    float lS = l_r + ML[wvL*16 + lr];
    float lS_o[4];
    #pragma unroll
    for (int r=0;r<4;++r) lS_o[r] = __shfl(lS, 4*gq + r);
    #pragma unroll
    for (int r=0;r<4;++r){
      int orow = wvL*16 + 4*gq + r;
      float v0 = (o0[r] + MO[orow*34 + lr])      / lS_o[r];
      float v1 = (o1[r] + MO[orow*34 + 16 + lr]) / lS_o[r];
      size_t ob = (size_t)(b*2048 + q0 + orow)*512 + h*32;
      Out[ob + lr]      = f2bf(v0);
      Out[ob + 16 + lr] = f2bf(v1);
    }
  }
}

// ---------- workspace layout (bytes) ----------
#define WS_B2   0u
#define WS_WT   8192u                                // 1536*1024*2 = 3145728
#define WS_W2T  (WS_WT + 3145728u)                   // 1024*512*2  = 1048576
#define WS_XB   (WS_W2T + 1048576u)                  // 4096*1024*2 = 8388608
#define WS_QKV  (WS_XB + 8388608u)                   // 4096*1536*2 = 12582912
#define WS_VT   (WS_QKV + 12582912u)                 // 1024*2048*2 = 4194304
#define WS_ATT  (WS_VT + 4194304u)                   // 4096*512*2  = 4194304

extern "C" void kernel_launch(void* const* d_in, const int* in_sizes, int n_in,
                              void* d_out, int out_size, void* d_ws, size_t ws_size,
                              hipStream_t stream) {
  const float* x  = (const float*)d_in[0];
  const float* Wa = (const float*)d_in[1];
  const float* ba = (const float*)d_in[2];
  const float* Wp = (const float*)d_in[3];
  const float* bp = (const float*)d_in[4];
  const float* kc = (const float*)d_in[5];
  const float* ke = (const float*)d_in[6];
  const float* vc = (const float*)d_in[7];
  const float* ve = (const float*)d_in[8];
  float* out = (float*)d_out;
  char* ws = (char*)d_ws;
  float* b2  = (float*)(ws + WS_B2);
  u16* Wt    = (u16*)(ws + WS_WT);
  u16* W2t   = (u16*)(ws + WS_W2T);
  u16* Xb    = (u16*)(ws + WS_XB);
  u16* QKVb  = (u16*)(ws + WS_QKV);
  u16* Vt    = (u16*)(ws + WS_VT);
  u16* Att   = (u16*)(ws + WS_ATT);

  convert_x<<<4096, 256, 0, stream>>>(x, Xb, 1048576);
  fold_bias<<<3, 256, 0, stream>>>(ba, kc, ke, vc, b2);
  fold_proj<<<dim3(8,16), 256, 0, stream>>>(Wp, ve, W2t);
  fold_qkv<<<768, 256, 0, stream>>>(Wa, kc, ke, vc, Wt);
  gemm64<u16><<<dim3(64,12), 256, 0, stream>>>(Xb, Wt, b2, QKVb, 4096, 1536, 1024, 1536);
  v_transpose_lat<<<dim3(32,32), 256, 0, stream>>>(QKVb, Vt);
  attn_fwd<<<dim3(32,32), 512, 0, stream>>>(QKVb, Vt, Att);
  gemm64<float><<<dim3(64,8), 256, 0, stream>>>(Att, W2t, bp, out, 4096, 1024, 512, 1024);
}

// Round 13
// 85.641 us; speedup vs baseline: 1.0698x; 1.0520x over previous
//
#include <hip/hip_runtime.h>
#include <cstddef>

typedef __attribute__((ext_vector_type(8))) __bf16 bf16x8;
typedef __attribute__((ext_vector_type(4))) float f32x4;
typedef unsigned short u16;
typedef unsigned int   u32;

#define SCLF (0.125f * 1.44269504f)   // softmax scale * log2(e), folded into q' weights

// ---------- helpers ----------
__device__ __forceinline__ u16 f2bf(float f){
  union { float f; u32 u; } v; v.f = f;
  u32 r = v.u + 0x7FFFu + ((v.u >> 16) & 1u);   // RNE
  return (u16)(r >> 16);
}
__device__ __forceinline__ u32 cvtpk(float lo, float hi){
  u32 r; asm("v_cvt_pk_bf16_f32 %0, %1, %2" : "=v"(r) : "v"(lo), "v"(hi)); return r;
}
__device__ __forceinline__ void gll16(const void* g, void* l){
  __builtin_amdgcn_global_load_lds((__attribute__((address_space(1))) void*)g,
                                   (__attribute__((address_space(3))) void*)l, 16, 0, 0);
}

// ---------- prep: x fp32 -> bf16 (vectorized) ----------
__global__ void convert_x(const float* __restrict__ x, u16* __restrict__ o, int n4){
  int i = blockIdx.x*blockDim.x + threadIdx.x;
  if (i >= n4) return;
  float4 v = ((const float4*)x)[i];
  ushort4 r; r.x = f2bf(v.x); r.y = f2bf(v.y); r.z = f2bf(v.z); r.w = f2bf(v.w);
  ((ushort4*)o)[i] = r;
}

// ---------- fold_qkvb: Wt[1536][1024] bf16 (768 blocks) + b2[1536] (3 blocks) ----------
// part0: q' rows h*32+r = sum_d Wa[c][h*64+d]*ke[r][d]*SCLF
// part1: k_lat rows 512+h*32+r = sum_d Wa[c][1024+h*64+d]*kc[d][r]
// part2: v_lat rows 1024+h*32+r = sum_d Wa[c][2048+h*64+d]*vc[d][r]
__global__ __launch_bounds__(256) void fold_qkvb(const float* __restrict__ Wa,
      const float* __restrict__ ba,
      const float* __restrict__ kc, const float* __restrict__ ke,
      const float* __restrict__ vc, u16* __restrict__ Wt, float* __restrict__ b2){
  __shared__ float WaL[64*65];   // [c][d] stride 65 (bank c+d, 2-way free)
  __shared__ float Ws[2048];     // flat copy of M (native layout)
  const int bid = blockIdx.x;
  const int tid = threadIdx.x;
  if (bid < 768){
    const int part = bid >> 8, rem = bid & 255, h = rem >> 4, cc = rem & 15;
    {
      const float* msrc = (part==0) ? ke : (part==1) ? kc : vc;
      *(float4*)&Ws[tid*4]        = ((const float4*)msrc)[tid];
      *(float4*)&Ws[1024 + tid*4] = ((const float4*)msrc)[tid + 256];
    }
    const int c0 = cc*64, off = part*1024 + h*64;
    {
      int r0 = tid >> 4, c4 = (tid & 15) * 4;
      #pragma unroll
      for (int i=0;i<4;++i){
        int row = i*16 + r0;
        float4 v = *(const float4*)&Wa[(size_t)(c0+row)*3072 + off + c4];
        WaL[row*65 + c4 + 0] = v.x;
        WaL[row*65 + c4 + 1] = v.y;
        WaL[row*65 + c4 + 2] = v.z;
        WaL[row*65 + c4 + 3] = v.w;
      }
    }
    __syncthreads();
    const int c = tid & 63, rg = tid >> 6;      // wave-uniform rg -> Ws reads broadcast
    float acc[8] = {};
    if (part == 0){
      for (int d=0; d<64; ++d){
        float a = WaL[c*65 + d];
        #pragma unroll
        for (int rr=0;rr<8;++rr) acc[rr] += a * Ws[(rg*8+rr)*64 + d];   // ke[r][d]
      }
    } else {
      for (int d=0; d<64; ++d){
        float a = WaL[c*65 + d];
        #pragma unroll
        for (int rr=0;rr<8;++rr) acc[rr] += a * Ws[d*32 + rg*8 + rr];   // kc/vc[d][r]
      }
    }
    const float scl = (part==0) ? SCLF : 1.f;
    const int nbase = part*512 + h*32 + rg*8;
    #pragma unroll
    for (int rr=0;rr<8;++rr)
      Wt[(size_t)(nbase+rr)*1024 + c0 + c] = f2bf(acc[rr]*scl);
  } else {
    // bias fold: block 768+part
    const int part = bid - 768;
    float* BaL  = Ws;       // 1024 floats
    float* W65  = WaL;      // [32 r][65] padded
    *(float4*)&BaL[tid*4] = *(const float4*)&ba[part*1024 + tid*4];
    {
      const float* msrc = (part==0) ? ke : (part==1) ? kc : vc;
      #pragma unroll
      for (int i=0;i<8;++i){
        int idx = tid + i*256;
        float v = msrc[idx];
        int r, d;
        if (part == 0){ r = idx >> 6; d = idx & 63; }      // ke[r][d]
        else          { d = idx >> 5; r = idx & 31; }      // kc/vc[d][r]
        W65[r*65 + d] = v;
      }
    }
    __syncthreads();
    const float scl = (part==0) ? SCLF : 1.f;
    #pragma unroll
    for (int t=0;t<2;++t){
      int l = tid + t*256;            // local output in [0,512)
      int hh = l >> 5, r = l & 31;
      float acc = 0.f;
      for (int d=0;d<64;++d) acc += BaL[hh*64 + d] * W65[r*65 + d];
      b2[part*512 + l] = acc * scl;
    }
  }
}

// ---------- fold_proj: W2t[j][h*32+r] = sum_d ve[r][d]*Wp[h*64+d][j] ----------
__global__ __launch_bounds__(256) void fold_proj(const float* __restrict__ Wp,
      const float* __restrict__ ve, u16* __restrict__ W2t){
  __shared__ float WpL[8192];   // [64 d][128 j]
  __shared__ float WeL[2048];   // [32 r][64 d] (native ve layout)
  const int jc = blockIdx.x, h = blockIdx.y;
  const int tid = threadIdx.x;
  {
    int dd = tid >> 5, c4 = (tid & 31) * 4;
    #pragma unroll
    for (int i=0;i<8;++i){
      int d = i*8 + dd;
      *(float4*)&WpL[d*128 + c4] = *(const float4*)&Wp[(size_t)(h*64+d)*1024 + jc*128 + c4];
    }
    *(float4*)&WeL[tid*4]        = ((const float4*)ve)[tid];
    *(float4*)&WeL[1024 + tid*4] = ((const float4*)ve)[tid + 256];
  }
  __syncthreads();
  const int jj = tid & 127, rg = tid >> 7;
  float out[16] = {};
  for (int d=0; d<64; ++d){
    float pv = WpL[d*128 + jj];
    #pragma unroll
    for (int rr=0; rr<16; ++rr) out[rr] += WeL[(rg*16+rr)*64 + d] * pv;
  }
  #pragma unroll
  for (int rr=0; rr<16; ++rr)
    W2t[(size_t)(jc*128 + jj)*512 + h*32 + rg*16 + rr] = f2bf(out[rr]);
}

// ---------- 64x128 bf16 GEMM (2-phase, gll16 both operands): C = A*Bt^T + bias ----------
// gemm1 (Vt != nullptr): blocks with n0 >= 1024 (v_lat) write the transposed,
// k-slot-permuted Vt[b*512 + nlat][p(t)] directly instead of C (fused v_transpose).
template<typename OT>
__global__ __launch_bounds__(256) void gemm64(const u16* __restrict__ A, const u16* __restrict__ Bt,
        const float* __restrict__ bias, OT* __restrict__ C, u16* __restrict__ Vt,
        int M, int N, int K, int ldc){
  __shared__ u16 As[64*64];     // 8 chunks
  __shared__ u16 Bs[128*64];    // 16 chunks
  const int nwg = gridDim.x * gridDim.y;
  const int id  = blockIdx.x + gridDim.x * blockIdx.y;
  const int nid = (id & 7) * (nwg >> 3) + (id >> 3);   // nwg % 8 == 0
  const int bx = nid % gridDim.x, by = nid / gridDim.x;
  const int tid = threadIdx.x, wv = tid>>6, ln = tid&63;
  const int lr = ln&15, g8 = (ln>>4)*8;
  const int m0 = bx*64, n0 = by*128;
  const int wr = (wv>>1)*32, wc = (wv&1)*64;
  const int lrow = ln>>3, lcol = (ln&7)*8;
  f32x4 acc[2][4] = {};
  const int nk = K >> 6;
  for (int kt=0; kt<nk; ++kt){
    #pragma unroll
    for (int it=0; it<6; ++it){
      int chunk = wv*6 + it;                  // 0..23: first 8 A, rest B
      if (chunk < 8){
        int row = chunk*8 + lrow;
        gll16(A + (size_t)(m0+row)*K + kt*64 + lcol, &As[chunk*512]);
      } else {
        int bc = chunk - 8;
        int row = bc*8 + lrow;
        gll16(Bt + (size_t)(n0+row)*K + kt*64 + lcol, &Bs[bc*512]);
      }
    }
    __syncthreads();
    #pragma unroll
    for (int ks=0; ks<2; ++ks){
      bf16x8 af[2], bfr[4];
      #pragma unroll
      for (int mt=0;mt<2;++mt) af[mt]  = *(const bf16x8*)&As[(wr+mt*16+lr)*64 + ks*32 + g8];
      #pragma unroll
      for (int nt=0;nt<4;++nt) bfr[nt] = *(const bf16x8*)&Bs[(wc+nt*16+lr)*64 + ks*32 + g8];
      #pragma unroll
      for (int mt=0;mt<2;++mt)
        #pragma unroll
        for (int nt=0;nt<4;++nt)
          acc[mt][nt] = __builtin_amdgcn_mfma_f32_16x16x32_bf16(af[mt], bfr[nt], acc[mt][nt], 0,0,0);
    }
    __syncthreads();
  }
  if (Vt && n0 >= 1024){
    // fused V-transpose epilogue: value for t lands at permuted position
    // p(t) = (t&3) + 4*((t>>4)&1) + 8*((t>>2)&3) + 32*((t&2047)>>5)
    #pragma unroll
    for (int mt=0;mt<2;++mt){
      int row0 = m0 + wr + mt*16 + 4*(ln>>4);          // t of acc[..][0]; +r contiguous
      int tin  = row0 & 2047;
      int p0 = 4*((tin>>4)&1) + 8*((tin>>2)&3) + 32*(tin>>5);
      size_t vbase = (size_t)(row0 >> 11) * 512;       // batch*512
      #pragma unroll
      for (int nt=0;nt<4;++nt){
        int col = n0 + wc + nt*16 + lr;
        float bv = bias[col];
        int nlat = col - 1024;
        union { u16 s[4]; uint2 v; } pk;
        #pragma unroll
        for (int r=0;r<4;++r) pk.s[r] = f2bf(acc[mt][nt][r] + bv);
        *(uint2*)&Vt[(vbase + nlat)*2048 + p0] = pk.v;
      }
    }
  } else {
    #pragma unroll
    for (int mt=0;mt<2;++mt){
      int row = m0 + wr + mt*16 + 4*(ln>>4);
      #pragma unroll
      for (int nt=0;nt<4;++nt){
        int col = n0 + wc + nt*16 + lr;
        float bv = bias[col];
        #pragma unroll
        for (int r=0;r<4;++r){
          float v = acc[mt][nt][r] + bv;
          if constexpr (sizeof(OT) == 2) C[(size_t)(row+r)*ldc + col] = f2bf(v);
          else                           C[(size_t)(row+r)*ldc + col] = v;
        }
      }
    }
  }
}

// ---------- causal flash attention in rank-32 latent space ----------
// QKV'[4096][1536]: q' (SCLF-scaled) at 0, k_lat at 512 (+h*32); v_lat region unused.
// Vt[bh*32+r][2048] permuted (written by gemm1's fused epilogue). Out = Att[4096][512].
// No-max softmax (bounded scores). grid (bh=32, y=32) qt=31-y (LPT);
// 512 thr = 2 subgroups x 4 waves, kt ≡ sg (mod 2), in-LDS merge.
__global__ __launch_bounds__(512, 8) void attn_fwd(const u16* __restrict__ QKV,
            const u16* __restrict__ Vt, u16* __restrict__ Out){
  const int bh = blockIdx.x;
  const int qt = 31 - blockIdx.y;
  const int b = bh >> 4, h = bh & 15;
  const int tid = threadIdx.x, wv = tid>>6, ln = tid&63;
  const int sg = wv>>2, wvL = wv&3;
  const int lr = ln&15, gq = ln>>4;
  __shared__ __align__(16) char SMEM[32768];
  u16* KB0 = (u16*)SMEM           + (sg*2    )*2048;   // 4 KB tiles [64 kv][32 d]
  u16* KB1 = (u16*)SMEM           + (sg*2 + 1)*2048;
  u16* VB0 = (u16*)(SMEM + 16384) + (sg*2    )*2048;   // 4 KB tiles [32 r][64 kv-perm]
  u16* VB1 = (u16*)(SMEM + 16384) + (sg*2 + 1)*2048;
  const int q0 = qt*64;
  const size_t base = (size_t)(b*2048) * 1536;
  bf16x8 qf = *(const bf16x8*)(QKV + base + (size_t)(q0 + wvL*16 + lr)*1536 + h*32 + gq*8);
  const int qglob = q0 + wvL*16 + lr;
  f32x4 o0 = {}, o1 = {};
  float l_r = 0.f;
  const u16* ksrc = QKV + base + 512 + h*32;
  const u16* vsrc = Vt + (size_t)(bh*32)*2048;

  const int ci = wvL*64 + ln;
  const int rK = ci>>2, cK = 8*((ci&3) ^ (rK&3));      // K row 64B: swz bits[5:4]
  const int rV = ci>>3, cV = 8*((ci&7) ^ (rV&7));      // V row 128B: swz bits[6:4]

  int offK[4], offV[2][2];
  #pragma unroll
  for (int nt=0;nt<4;++nt)
    offK[nt] = (nt*16+lr)*64 + ((gq*16) ^ ((lr&3)<<4));
  #pragma unroll
  for (int dt=0;dt<2;++dt)
    #pragma unroll
    for (int c=0;c<2;++c)
      offV[dt][c] = (dt*16+lr)*128 + ((c*64 + gq*16) ^ ((lr&7)<<4));

  if (sg <= qt){
    gll16(ksrc + (size_t)(sg*64 + rK)*1536 + cK, KB0 + wvL*512);
    gll16(vsrc + (size_t)rV*2048 + sg*64 + cV,   VB0 + wvL*512);
  }
  __syncthreads();
  const u16* kp = ksrc + (size_t)(sg*64 + 128 + rK)*1536 + cK;
  const u16* vp = vsrc + (size_t)rV*2048 + sg*64 + 128 + cV;
  const size_t KSTEP = (size_t)128*1536;

  #define ABODY(II, KBC, VBC, KBN, VBN) do { \
    const int kt = 2*(II) + sg; \
    if (kt + 2 <= qt){ \
      gll16(kp, (KBN) + wvL*512); \
      gll16(vp, (VBN) + wvL*512); \
      kp += KSTEP; vp += 128; \
    } \
    if (kt <= qt){ \
      f32x4 s4[4] = {}; \
      __builtin_amdgcn_s_setprio(1); \
      _Pragma("unroll") for (int nt=0;nt<4;++nt){ \
        bf16x8 k0 = *(const bf16x8*)((const char*)(KBC) + offK[nt]); \
        s4[nt] = __builtin_amdgcn_mfma_f32_16x16x32_bf16(k0, qf, s4[nt], 0,0,0); \
      } \
      __builtin_amdgcn_s_setprio(0); \
      if (kt == qt){ \
        const int kv0 = kt*64; \
        _Pragma("unroll") for (int nt=0;nt<4;++nt) \
        _Pragma("unroll") for (int r=0;r<4;++r){ \
          int k = kv0 + nt*16 + 4*gq + r; \
          if (k > qglob) s4[nt][r] = -1e30f; \
        } \
      } \
      float p0,p1,p2,p3,p4,p5,p6,p7; \
      p0=__builtin_amdgcn_exp2f(s4[0][0]); p1=__builtin_amdgcn_exp2f(s4[0][1]); \
      p2=__builtin_amdgcn_exp2f(s4[0][2]); p3=__builtin_amdgcn_exp2f(s4[0][3]); \
      p4=__builtin_amdgcn_exp2f(s4[1][0]); p5=__builtin_amdgcn_exp2f(s4[1][1]); \
      p6=__builtin_amdgcn_exp2f(s4[1][2]); p7=__builtin_amdgcn_exp2f(s4[1][3]); \
      l_r += ((p0+p1)+(p2+p3)) + ((p4+p5)+(p6+p7)); \
      union { u32 u[4]; bf16x8 v; } pa0, pa1; \
      pa0.u[0]=cvtpk(p0,p1); pa0.u[1]=cvtpk(p2,p3); pa0.u[2]=cvtpk(p4,p5); pa0.u[3]=cvtpk(p6,p7); \
      p0=__builtin_amdgcn_exp2f(s4[2][0]); p1=__builtin_amdgcn_exp2f(s4[2][1]); \
      p2=__builtin_amdgcn_exp2f(s4[2][2]); p3=__builtin_amdgcn_exp2f(s4[2][3]); \
      p4=__builtin_amdgcn_exp2f(s4[3][0]); p5=__builtin_amdgcn_exp2f(s4[3][1]); \
      p6=__builtin_amdgcn_exp2f(s4[3][2]); p7=__builtin_amdgcn_exp2f(s4[3][3]); \
      l_r += ((p0+p1)+(p2+p3)) + ((p4+p5)+(p6+p7)); \
      pa1.u[0]=cvtpk(p0,p1); pa1.u[1]=cvtpk(p2,p3); pa1.u[2]=cvtpk(p4,p5); pa1.u[3]=cvtpk(p6,p7); \
      __builtin_amdgcn_s_setprio(1); \
      o0 = __builtin_amdgcn_mfma_f32_16x16x32_bf16(pa0.v, *(const bf16x8*)((const char*)(VBC) + offV[0][0]), o0, 0,0,0); \
      o1 = __builtin_amdgcn_mfma_f32_16x16x32_bf16(pa0.v, *(const bf16x8*)((const char*)(VBC) + offV[1][0]), o1, 0,0,0); \
      o0 = __builtin_amdgcn_mfma_f32_16x16x32_bf16(pa1.v, *(const bf16x8*)((const char*)(VBC) + offV[0][1]), o0, 0,0,0); \
      o1 = __builtin_amdgcn_mfma_f32_16x16x32_bf16(pa1.v, *(const bf16x8*)((const char*)(VBC) + offV[1][1]), o1, 0,0,0); \
      __builtin_amdgcn_s_setprio(0); \
    } \
    __syncthreads(); \
  } while(0)

  const int nmax = (qt + 2) >> 1;
  const int jmax = (nmax + 1) >> 1;
  for (int j = 0; j < jmax; ++j){
    ABODY(2*j,   KB0, VB0, KB1, VB1);
    ABODY(2*j+1, KB1, VB1, KB0, VB0);
  }
  l_r += __shfl_xor(l_r, 16);
  l_r += __shfl_xor(l_r, 32);

  // ---- in-LDS merge of the two partial (unnormalized) results ----
  float* MO = (float*)SMEM;               // [64][34] padded
  float* ML = (float*)(SMEM + 12288);     // l[64]
  if (sg == 1){
    #pragma unroll
    for (int r=0;r<4;++r){
      MO[(wvL*16 + 4*gq + r)*34 + lr]      = o0[r];
      MO[(wvL*16 + 4*gq + r)*34 + 16 + lr] = o1[r];
    }
    if (gq == 0) ML[wvL*16 + lr] = l_r;
  }
  __syncthreads();
  if (sg == 0){
    float lS = l_r + ML[wvL*16 + lr];
    float lS_o[4];
    #pragma unroll
    for (int r=0;r<4;++r) lS_o[r] = __shfl(lS, 4*gq + r);
    #pragma unroll
    for (int r=0;r<4;++r){
      int orow = wvL*16 + 4*gq + r;
      float v0 = (o0[r] + MO[orow*34 + lr])      / lS_o[r];
      float v1 = (o1[r] + MO[orow*34 + 16 + lr]) / lS_o[r];
      size_t ob = (size_t)(b*2048 + q0 + orow)*512 + h*32;
      Out[ob + lr]      = f2bf(v0);
      Out[ob + 16 + lr] = f2bf(v1);
    }
  }
}

// ---------- workspace layout (bytes) ----------
#define WS_B2   0u
#define WS_WT   8192u                                // 1536*1024*2 = 3145728
#define WS_W2T  (WS_WT + 3145728u)                   // 1024*512*2  = 1048576
#define WS_XB   (WS_W2T + 1048576u)                  // 4096*1024*2 = 8388608
#define WS_QKV  (WS_XB + 8388608u)                   // 4096*1536*2 = 12582912
#define WS_VT   (WS_QKV + 12582912u)                 // 1024*2048*2 = 4194304
#define WS_ATT  (WS_VT + 4194304u)                   // 4096*512*2  = 4194304

extern "C" void kernel_launch(void* const* d_in, const int* in_sizes, int n_in,
                              void* d_out, int out_size, void* d_ws, size_t ws_size,
                              hipStream_t stream) {
  const float* x  = (const float*)d_in[0];
  const float* Wa = (const float*)d_in[1];
  const float* ba = (const float*)d_in[2];
  const float* Wp = (const float*)d_in[3];
  const float* bp = (const float*)d_in[4];
  const float* kc = (const float*)d_in[5];
  const float* ke = (const float*)d_in[6];
  const float* vc = (const float*)d_in[7];
  const float* ve = (const float*)d_in[8];
  float* out = (float*)d_out;
  char* ws = (char*)d_ws;
  float* b2  = (float*)(ws + WS_B2);
  u16* Wt    = (u16*)(ws + WS_WT);
  u16* W2t   = (u16*)(ws + WS_W2T);
  u16* Xb    = (u16*)(ws + WS_XB);
  u16* QKVb  = (u16*)(ws + WS_QKV);
  u16* Vt    = (u16*)(ws + WS_VT);
  u16* Att   = (u16*)(ws + WS_ATT);

  convert_x<<<4096, 256, 0, stream>>>(x, Xb, 1048576);
  fold_qkvb<<<771, 256, 0, stream>>>(Wa, ba, kc, ke, vc, Wt, b2);
  fold_proj<<<dim3(8,16), 256, 0, stream>>>(Wp, ve, W2t);
  gemm64<u16><<<dim3(64,12), 256, 0, stream>>>(Xb, Wt, b2, QKVb, Vt, 4096, 1536, 1024, 1536);
  attn_fwd<<<dim3(32,32), 512, 0, stream>>>(QKVb, Vt, Att);
  gemm64<float><<<dim3(64,8), 256, 0, stream>>>(Att, W2t, bp, out, (u16*)nullptr, 4096, 1024, 512, 1024);
}

// Round 14
// 84.128 us; speedup vs baseline: 1.0891x; 1.0180x over previous
//
#include <hip/hip_runtime.h>
#include <cstddef>

typedef __attribute__((ext_vector_type(8))) __bf16 bf16x8;
typedef __attribute__((ext_vector_type(4))) float f32x4;
typedef unsigned short u16;
typedef unsigned int   u32;

#define SCLF (0.125f * 1.44269504f)   // softmax scale * log2(e), baked into q' master weights

// ---------- helpers ----------
__device__ __forceinline__ u16 f2bf(float f){
  union { float f; u32 u; } v; v.f = f;
  u32 r = v.u + 0x7FFFu + ((v.u >> 16) & 1u);   // RNE
  return (u16)(r >> 16);
}
__device__ __forceinline__ u32 cvtpk(float lo, float hi){
  u32 r; asm("v_cvt_pk_bf16_f32 %0, %1, %2" : "=v"(r) : "v"(lo), "v"(hi)); return r;
}
__device__ __forceinline__ void gll16(const void* g, void* l){
  __builtin_amdgcn_global_load_lds((__attribute__((address_space(1))) void*)g,
                                   (__attribute__((address_space(3))) void*)l, 16, 0, 0);
}

// ---------- convert_all: x->bf16 | Wa->bf16 | masters->bf16 | bias fold ----------
// grid: [0,4096) x | [4096,7168) Wa | 7168 masters | [7169,7172) bias
__global__ __launch_bounds__(256) void convert_all(const float* __restrict__ x,
      const float* __restrict__ Wa, const float* __restrict__ ba,
      const float* __restrict__ kc, const float* __restrict__ ke,
      const float* __restrict__ vc, const float* __restrict__ ve,
      u16* __restrict__ Xb, u16* __restrict__ Wab, u16* __restrict__ Mb,
      float* __restrict__ b2){
  __shared__ float BaL[1024];
  __shared__ float W65[32*65];
  const int bid = blockIdx.x, tid = threadIdx.x;
  if (bid < 4096){
    int i = bid*256 + tid;
    float4 v = ((const float4*)x)[i];
    ushort4 r; r.x=f2bf(v.x); r.y=f2bf(v.y); r.z=f2bf(v.z); r.w=f2bf(v.w);
    ((ushort4*)Xb)[i] = r;
  } else if (bid < 7168){
    int i = (bid-4096)*256 + tid;
    float4 v = ((const float4*)Wa)[i];
    ushort4 r; r.x=f2bf(v.x); r.y=f2bf(v.y); r.z=f2bf(v.z); r.w=f2bf(v.w);
    ((ushort4*)Wab)[i] = r;
  } else if (bid == 7168){
    // Mb[0..2047] = ke*SCLF [r][d]; [2048..4095] = kc^T [r][d]; [4096..6143] = vc^T;
    // [6144..8191] = ve [r][d] native
    #pragma unroll
    for (int t=0;t<8;++t){
      int idx = t*256 + tid;              // 0..2047
      Mb[idx] = f2bf(ke[idx]*SCLF);       // ke native [r*64+d]
      int d = idx>>5, r = idx&31;         // kc/vc native [d*32+r]
      Mb[2048 + r*64 + d] = f2bf(kc[idx]);
      Mb[4096 + r*64 + d] = f2bf(vc[idx]);
      Mb[6144 + idx] = f2bf(ve[idx]);     // ve native [r*64+d]
    }
  } else {
    // bias fold (exact f32 math, unchanged): part = bid-7169
    const int part = bid - 7169;
    *(float4*)&BaL[tid*4] = *(const float4*)&ba[part*1024 + tid*4];
    {
      const float* msrc = (part==0) ? ke : (part==1) ? kc : vc;
      #pragma unroll
      for (int i=0;i<8;++i){
        int idx = tid + i*256;
        float v = msrc[idx];
        int r, d;
        if (part == 0){ r = idx >> 6; d = idx & 63; }
        else          { d = idx >> 5; r = idx & 31; }
        W65[r*65 + d] = v;
      }
    }
    __syncthreads();
    const float scl = (part==0) ? SCLF : 1.f;
    #pragma unroll
    for (int t=0;t<2;++t){
      int l = tid + t*256;
      int hh = l >> 5, r = l & 31;
      float acc = 0.f;
      for (int d=0;d<64;++d) acc += BaL[hh*64 + d] * W65[r*65 + d];
      b2[part*512 + l] = acc * scl;
    }
  }
}

// ---------- transpose_cvt: dst[n][c] = f2bf(src[c][n]), 64x64 tiles (proven R0 kernel) ----------
__global__ __launch_bounds__(256) void transpose_cvt(const float* __restrict__ src, int ld_src,
            u16* __restrict__ dst, int ld_dst){
  __shared__ float tile[64][65];
  int c0 = blockIdx.x*64, n0 = blockIdx.y*64;
  int tx = threadIdx.x & 63, ty = threadIdx.x >> 6;
  #pragma unroll 4
  for (int k=0;k<16;++k){
    int r = 4*k + ty;
    tile[r][tx] = src[(size_t)(c0+r)*ld_src + n0 + tx];
  }
  __syncthreads();
  #pragma unroll 4
  for (int k=0;k<16;++k){
    int r = 4*k + ty;
    dst[(size_t)(n0+r)*ld_dst + c0 + tx] = f2bf(tile[tx][r]);
  }
}

// ---------- fold_gemm_qkv: Wt[(ph>>4)*512+(ph&15)*32+r][c] = sum_d Wab[c][ph*64+d]*Mb_part[r][d] ----------
// MFMA mini-GEMM, 64c x 32r per block, K=64. grid (16, 48).
__global__ __launch_bounds__(256) void fold_gemm_qkv(const u16* __restrict__ Wab,
      const u16* __restrict__ Mb, u16* __restrict__ Wt){
  __shared__ u16 As[4096];   // [64 c][64 d]
  __shared__ u16 Bs[2048];   // [32 r][64 d]
  const int cc = blockIdx.x, ph = blockIdx.y;
  const int tid = threadIdx.x, wv = tid>>6, ln = tid&63;
  const int lr = ln&15, g8 = (ln>>4)*8, gq = ln>>4;
  const int c0 = cc*64;
  const u16* A = Wab + (size_t)c0*3072 + ph*64;
  const u16* B = Mb + (ph>>4)*2048;
  const int lrow = ln>>3, lcol = (ln&7)*8;
  #pragma unroll
  for (int it=0;it<3;++it){
    int c3 = wv*3 + it;                  // 12 chunks: 0-7 A, 8-11 B
    if (c3 < 8) gll16(A + (size_t)(c3*8+lrow)*3072 + lcol, &As[c3*512]);
    else { int bc = c3-8; gll16(B + (bc*8+lrow)*64 + lcol, &Bs[bc*512]); }
  }
  __syncthreads();
  f32x4 acc[2] = {};
  const int wr = (wv>>1)*32, wn = wv&1;
  #pragma unroll
  for (int ks=0;ks<2;++ks){
    bf16x8 bf = *(const bf16x8*)&Bs[(wn*16+lr)*64 + ks*32 + g8];
    #pragma unroll
    for (int mt=0;mt<2;++mt){
      bf16x8 af = *(const bf16x8*)&As[(wr+mt*16+lr)*64 + ks*32 + g8];
      acc[mt] = __builtin_amdgcn_mfma_f32_16x16x32_bf16(af, bf, acc[mt], 0,0,0);
    }
  }
  const int n = (ph>>4)*512 + (ph&15)*32 + wn*16 + lr;
  #pragma unroll
  for (int mt=0;mt<2;++mt){
    union { u16 s[4]; uint2 v; } pk;
    #pragma unroll
    for (int r=0;r<4;++r) pk.s[r] = f2bf(acc[mt][r]);
    *(uint2*)&Wt[(size_t)n*1024 + c0 + wr + mt*16 + 4*gq] = pk.v;
  }
}

// ---------- fold_gemm_proj: W2t[j][ph*32+r] = sum_d WpTb[j][ph*64+d]*veb[r][d] ----------
// grid (16, 16).
__global__ __launch_bounds__(256) void fold_gemm_proj(const u16* __restrict__ WpTb,
      const u16* __restrict__ veb, u16* __restrict__ W2t){
  __shared__ u16 As[4096];   // [64 j][64 d]
  __shared__ u16 Bs[2048];   // [32 r][64 d]
  const int cc = blockIdx.x, ph = blockIdx.y;
  const int tid = threadIdx.x, wv = tid>>6, ln = tid&63;
  const int lr = ln&15, g8 = (ln>>4)*8, gq = ln>>4;
  const int c0 = cc*64;
  const u16* A = WpTb + (size_t)c0*1024 + ph*64;
  const int lrow = ln>>3, lcol = (ln&7)*8;
  #pragma unroll
  for (int it=0;it<3;++it){
    int c3 = wv*3 + it;
    if (c3 < 8) gll16(A + (size_t)(c3*8+lrow)*1024 + lcol, &As[c3*512]);
    else { int bc = c3-8; gll16(veb + (bc*8+lrow)*64 + lcol, &Bs[bc*512]); }
  }
  __syncthreads();
  f32x4 acc[2] = {};
  const int wr = (wv>>1)*32, wn = wv&1;
  #pragma unroll
  for (int ks=0;ks<2;++ks){
    bf16x8 bf = *(const bf16x8*)&Bs[(wn*16+lr)*64 + ks*32 + g8];
    #pragma unroll
    for (int mt=0;mt<2;++mt){
      bf16x8 af = *(const bf16x8*)&As[(wr+mt*16+lr)*64 + ks*32 + g8];
      acc[mt] = __builtin_amdgcn_mfma_f32_16x16x32_bf16(af, bf, acc[mt], 0,0,0);
    }
  }
  const int col = ph*32 + wn*16 + lr;
  #pragma unroll
  for (int mt=0;mt<2;++mt)
    #pragma unroll
    for (int r=0;r<4;++r)
      W2t[(size_t)(c0 + wr + mt*16 + 4*gq + r)*512 + col] = f2bf(acc[mt][r]);
}

// ---------- 64x128 bf16 GEMM (2-phase, gll16 both operands): C = A*Bt^T + bias ----------
// gemm1 (Vt != nullptr): blocks with n0 >= 1024 (v_lat) write the transposed,
// k-slot-permuted Vt[b*512 + nlat][p(t)] directly instead of C (fused v_transpose).
template<typename OT>
__global__ __launch_bounds__(256) void gemm64(const u16* __restrict__ A, const u16* __restrict__ Bt,
        const float* __restrict__ bias, OT* __restrict__ C, u16* __restrict__ Vt,
        int M, int N, int K, int ldc){
  __shared__ u16 As[64*64];     // 8 chunks
  __shared__ u16 Bs[128*64];    // 16 chunks
  const int nwg = gridDim.x * gridDim.y;
  const int id  = blockIdx.x + gridDim.x * blockIdx.y;
  const int nid = (id & 7) * (nwg >> 3) + (id >> 3);   // nwg % 8 == 0
  const int bx = nid % gridDim.x, by = nid / gridDim.x;
  const int tid = threadIdx.x, wv = tid>>6, ln = tid&63;
  const int lr = ln&15, g8 = (ln>>4)*8;
  const int m0 = bx*64, n0 = by*128;
  const int wr = (wv>>1)*32, wc = (wv&1)*64;
  const int lrow = ln>>3, lcol = (ln&7)*8;
  f32x4 acc[2][4] = {};
  const int nk = K >> 6;
  for (int kt=0; kt<nk; ++kt){
    #pragma unroll
    for (int it=0; it<6; ++it){
      int chunk = wv*6 + it;                  // 0..23: first 8 A, rest B
      if (chunk < 8){
        int row = chunk*8 + lrow;
        gll16(A + (size_t)(m0+row)*K + kt*64 + lcol, &As[chunk*512]);
      } else {
        int bc = chunk - 8;
        int row = bc*8 + lrow;
        gll16(Bt + (size_t)(n0+row)*K + kt*64 + lcol, &Bs[bc*512]);
      }
    }
    __syncthreads();
    #pragma unroll
    for (int ks=0; ks<2; ++ks){
      bf16x8 af[2], bfr[4];
      #pragma unroll
      for (int mt=0;mt<2;++mt) af[mt]  = *(const bf16x8*)&As[(wr+mt*16+lr)*64 + ks*32 + g8];
      #pragma unroll
      for (int nt=0;nt<4;++nt) bfr[nt] = *(const bf16x8*)&Bs[(wc+nt*16+lr)*64 + ks*32 + g8];
      #pragma unroll
      for (int mt=0;mt<2;++mt)
        #pragma unroll
        for (int nt=0;nt<4;++nt)
          acc[mt][nt] = __builtin_amdgcn_mfma_f32_16x16x32_bf16(af[mt], bfr[nt], acc[mt][nt], 0,0,0);
    }
    __syncthreads();
  }
  if (Vt && n0 >= 1024){
    // fused V-transpose epilogue: value for t lands at permuted position
    #pragma unroll
    for (int mt=0;mt<2;++mt){
      int row0 = m0 + wr + mt*16 + 4*(ln>>4);
      int tin  = row0 & 2047;
      int p0 = 4*((tin>>4)&1) + 8*((tin>>2)&3) + 32*(tin>>5);
      size_t vbase = (size_t)(row0 >> 11) * 512;
      #pragma unroll
      for (int nt=0;nt<4;++nt){
        int col = n0 + wc + nt*16 + lr;
        float bv = bias[col];
        int nlat = col - 1024;
        union { u16 s[4]; uint2 v; } pk;
        #pragma unroll
        for (int r=0;r<4;++r) pk.s[r] = f2bf(acc[mt][nt][r] + bv);
        *(uint2*)&Vt[(vbase + nlat)*2048 + p0] = pk.v;
      }
    }
  } else {
    #pragma unroll
    for (int mt=0;mt<2;++mt){
      int row = m0 + wr + mt*16 + 4*(ln>>4);
      #pragma unroll
      for (int nt=0;nt<4;++nt){
        int col = n0 + wc + nt*16 + lr;
        float bv = bias[col];
        #pragma unroll
        for (int r=0;r<4;++r){
          float v = acc[mt][nt][r] + bv;
          if constexpr (sizeof(OT) == 2) C[(size_t)(row+r)*ldc + col] = f2bf(v);
          else                           C[(size_t)(row+r)*ldc + col] = v;
        }
      }
    }
  }
}

// ---------- causal flash attention in rank-32 latent space ----------
__global__ __launch_bounds__(512, 8) void attn_fwd(const u16* __restrict__ QKV,
            const u16* __restrict__ Vt, u16* __restrict__ Out){
  const int bh = blockIdx.x;
  const int qt = 31 - blockIdx.y;
  const int b = bh >> 4, h = bh & 15;
  const int tid = threadIdx.x, wv = tid>>6, ln = tid&63;
  const int sg = wv>>2, wvL = wv&3;
  const int lr = ln&15, gq = ln>>4;
  __shared__ __align__(16) char SMEM[32768];
  u16* KB0 = (u16*)SMEM           + (sg*2    )*2048;
  u16* KB1 = (u16*)SMEM           + (sg*2 + 1)*2048;
  u16* VB0 = (u16*)(SMEM + 16384) + (sg*2    )*2048;
  u16* VB1 = (u16*)(SMEM + 16384) + (sg*2 + 1)*2048;
  const int q0 = qt*64;
  const size_t base = (size_t)(b*2048) * 1536;
  bf16x8 qf = *(const bf16x8*)(QKV + base + (size_t)(q0 + wvL*16 + lr)*1536 + h*32 + gq*8);
  const int qglob = q0 + wvL*16 + lr;
  f32x4 o0 = {}, o1 = {};
  float l_r = 0.f;
  const u16* ksrc = QKV + base + 512 + h*32;
  const u16* vsrc = Vt + (size_t)(bh*32)*2048;

  const int ci = wvL*64 + ln;
  const int rK = ci>>2, cK = 8*((ci&3) ^ (rK&3));
  const int rV = ci>>3, cV = 8*((ci&7) ^ (rV&7));

  int offK[4], offV[2][2];
  #pragma unroll
  for (int nt=0;nt<4;++nt)
    offK[nt] = (nt*16+lr)*64 + ((gq*16) ^ ((lr&3)<<4));
  #pragma unroll
  for (int dt=0;dt<2;++dt)
    #pragma unroll
    for (int c=0;c<2;++c)
      offV[dt][c] = (dt*16+lr)*128 + ((c*64 + gq*16) ^ ((lr&7)<<4));

  if (sg <= qt){
    gll16(ksrc + (size_t)(sg*64 + rK)*1536 + cK, KB0 + wvL*512);
    gll16(vsrc + (size_t)rV*2048 + sg*64 + cV,   VB0 + wvL*512);
  }
  __syncthreads();
  const u16* kp = ksrc + (size_t)(sg*64 + 128 + rK)*1536 + cK;
  const u16* vp = vsrc + (size_t)rV*2048 + sg*64 + 128 + cV;
  const size_t KSTEP = (size_t)128*1536;

  #define ABODY(II, KBC, VBC, KBN, VBN) do { \
    const int kt = 2*(II) + sg; \
    if (kt + 2 <= qt){ \
      gll16(kp, (KBN) + wvL*512); \
      gll16(vp, (VBN) + wvL*512); \
      kp += KSTEP; vp += 128; \
    } \
    if (kt <= qt){ \
      f32x4 s4[4] = {}; \
      __builtin_amdgcn_s_setprio(1); \
      _Pragma("unroll") for (int nt=0;nt<4;++nt){ \
        bf16x8 k0 = *(const bf16x8*)((const char*)(KBC) + offK[nt]); \
        s4[nt] = __builtin_amdgcn_mfma_f32_16x16x32_bf16(k0, qf, s4[nt], 0,0,0); \
      } \
      __builtin_amdgcn_s_setprio(0); \
      if (kt == qt){ \
        const int kv0 = kt*64; \
        _Pragma("unroll") for (int nt=0;nt<4;++nt) \
        _Pragma("unroll") for (int r=0;r<4;++r){ \
          int k = kv0 + nt*16 + 4*gq + r; \
          if (k > qglob) s4[nt][r] = -1e30f; \
        } \
      } \
      float p0,p1,p2,p3,p4,p5,p6,p7; \
      p0=__builtin_amdgcn_exp2f(s4[0][0]); p1=__builtin_amdgcn_exp2f(s4[0][1]); \
      p2=__builtin_amdgcn_exp2f(s4[0][2]); p3=__builtin_amdgcn_exp2f(s4[0][3]); \
      p4=__builtin_amdgcn_exp2f(s4[1][0]); p5=__builtin_amdgcn_exp2f(s4[1][1]); \
      p6=__builtin_amdgcn_exp2f(s4[1][2]); p7=__builtin_amdgcn_exp2f(s4[1][3]); \
      l_r += ((p0+p1)+(p2+p3)) + ((p4+p5)+(p6+p7)); \
      union { u32 u[4]; bf16x8 v; } pa0, pa1; \
      pa0.u[0]=cvtpk(p0,p1); pa0.u[1]=cvtpk(p2,p3); pa0.u[2]=cvtpk(p4,p5); pa0.u[3]=cvtpk(p6,p7); \
      p0=__builtin_amdgcn_exp2f(s4[2][0]); p1=__builtin_amdgcn_exp2f(s4[2][1]); \
      p2=__builtin_amdgcn_exp2f(s4[2][2]); p3=__builtin_amdgcn_exp2f(s4[2][3]); \
      p4=__builtin_amdgcn_exp2f(s4[3][0]); p5=__builtin_amdgcn_exp2f(s4[3][1]); \
      p6=__builtin_amdgcn_exp2f(s4[3][2]); p7=__builtin_amdgcn_exp2f(s4[3][3]); \
      l_r += ((p0+p1)+(p2+p3)) + ((p4+p5)+(p6+p7)); \
      pa1.u[0]=cvtpk(p0,p1); pa1.u[1]=cvtpk(p2,p3); pa1.u[2]=cvtpk(p4,p5); pa1.u[3]=cvtpk(p6,p7); \
      __builtin_amdgcn_s_setprio(1); \
      o0 = __builtin_amdgcn_mfma_f32_16x16x32_bf16(pa0.v, *(const bf16x8*)((const char*)(VBC) + offV[0][0]), o0, 0,0,0); \
      o1 = __builtin_amdgcn_mfma_f32_16x16x32_bf16(pa0.v, *(const bf16x8*)((const char*)(VBC) + offV[1][0]), o1, 0,0,0); \
      o0 = __builtin_amdgcn_mfma_f32_16x16x32_bf16(pa1.v, *(const bf16x8*)((const char*)(VBC) + offV[0][1]), o0, 0,0,0); \
      o1 = __builtin_amdgcn_mfma_f32_16x16x32_bf16(pa1.v, *(const bf16x8*)((const char*)(VBC) + offV[1][1]), o1, 0,0,0); \
      __builtin_amdgcn_s_setprio(0); \
    } \
    __syncthreads(); \
  } while(0)

  const int nmax = (qt + 2) >> 1;
  const int jmax = (nmax + 1) >> 1;
  for (int j = 0; j < jmax; ++j){
    ABODY(2*j,   KB0, VB0, KB1, VB1);
    ABODY(2*j+1, KB1, VB1, KB0, VB0);
  }
  l_r += __shfl_xor(l_r, 16);
  l_r += __shfl_xor(l_r, 32);

  float* MO = (float*)SMEM;               // [64][34] padded
  float* ML = (float*)(SMEM + 12288);     // l[64]
  if (sg == 1){
    #pragma unroll
    for (int r=0;r<4;++r){
      MO[(wvL*16 + 4*gq + r)*34 + lr]      = o0[r];
      MO[(wvL*16 + 4*gq + r)*34 + 16 + lr] = o1[r];
    }
    if (gq == 0) ML[wvL*16 + lr] = l_r;
  }
  __syncthreads();
  if (sg == 0){
    float lS = l_r + ML[wvL*16 + lr];
    float lS_o[4];
    #pragma unroll
    for (int r=0;r<4;++r) lS_o[r] = __shfl(lS, 4*gq + r);
    #pragma unroll
    for (int r=0;r<4;++r){
      int orow = wvL*16 + 4*gq + r;
      float v0 = (o0[r] + MO[orow*34 + lr])      / lS_o[r];
      float v1 = (o1[r] + MO[orow*34 + 16 + lr]) / lS_o[r];
      size_t ob = (size_t)(b*2048 + q0 + orow)*512 + h*32;
      Out[ob + lr]      = f2bf(v0);
      Out[ob + 16 + lr] = f2bf(v1);
    }
  }
}

// ---------- workspace layout (bytes) ----------
#define WS_B2   0u                                   // 1536*4 = 6144
#define WS_WT   8192u                                // 1536*1024*2 = 3145728
#define WS_W2T  (WS_WT + 3145728u)                   // 1024*512*2  = 1048576
#define WS_XB   (WS_W2T + 1048576u)                  // 4096*1024*2 = 8388608
#define WS_QKV  (WS_XB + 8388608u)                   // 4096*1536*2 = 12582912
#define WS_VT   (WS_QKV + 12582912u)                 // 1024*2048*2 = 4194304
#define WS_ATT  (WS_VT + 4194304u)                   // 4096*512*2  = 4194304
#define WS_WAB  (WS_ATT + 4194304u)                  // 1024*3072*2 = 6291456
#define WS_WPT  (WS_WAB + 6291456u)                  // 1024*1024*2 = 2097152
#define WS_MB   (WS_WPT + 2097152u)                  // 8192*2 = 16384

extern "C" void kernel_launch(void* const* d_in, const int* in_sizes, int n_in,
                              void* d_out, int out_size, void* d_ws, size_t ws_size,
                              hipStream_t stream) {
  const float* x  = (const float*)d_in[0];
  const float* Wa = (const float*)d_in[1];
  const float* ba = (const float*)d_in[2];
  const float* Wp = (const float*)d_in[3];
  const float* bp = (const float*)d_in[4];
  const float* kc = (const float*)d_in[5];
  const float* ke = (const float*)d_in[6];
  const float* vc = (const float*)d_in[7];
  const float* ve = (const float*)d_in[8];
  float* out = (float*)d_out;
  char* ws = (char*)d_ws;
  float* b2  = (float*)(ws + WS_B2);
  u16* Wt    = (u16*)(ws + WS_WT);
  u16* W2t   = (u16*)(ws + WS_W2T);
  u16* Xb    = (u16*)(ws + WS_XB);
  u16* QKVb  = (u16*)(ws + WS_QKV);
  u16* Vt    = (u16*)(ws + WS_VT);
  u16* Att   = (u16*)(ws + WS_ATT);
  u16* Wab   = (u16*)(ws + WS_WAB);
  u16* WpTb  = (u16*)(ws + WS_WPT);
  u16* Mb    = (u16*)(ws + WS_MB);
  u16* veb   = Mb + 6144;

  convert_all<<<7172, 256, 0, stream>>>(x, Wa, ba, kc, ke, vc, ve, Xb, Wab, Mb, b2);
  transpose_cvt<<<dim3(16,16), 256, 0, stream>>>(Wp, 1024, WpTb, 1024);
  fold_gemm_qkv<<<dim3(16,48), 256, 0, stream>>>(Wab, Mb, Wt);
  fold_gemm_proj<<<dim3(16,16), 256, 0, stream>>>(WpTb, veb, W2t);
  gemm64<u16><<<dim3(64,12), 256, 0, stream>>>(Xb, Wt, b2, QKVb, Vt, 4096, 1536, 1024, 1536);
  attn_fwd<<<dim3(32,32), 512, 0, stream>>>(QKVb, Vt, Att);
  gemm64<float><<<dim3(64,8), 256, 0, stream>>>(Att, W2t, bp, out, (u16*)nullptr, 4096, 1024, 512, 1024);
}

// Round 15
// 80.076 us; speedup vs baseline: 1.1442x; 1.0506x over previous
//
#include <hip/hip_runtime.h>
#include <cstddef>

typedef __attribute__((ext_vector_type(8))) __bf16 bf16x8;
typedef __attribute__((ext_vector_type(4))) float f32x4;
typedef unsigned short u16;
typedef unsigned int   u32;

#define SCLF (0.125f * 1.44269504f)   // softmax scale * log2(e), baked into q' master weights

// ---------- helpers ----------
__device__ __forceinline__ u16 f2bf(float f){
  union { float f; u32 u; } v; v.f = f;
  u32 r = v.u + 0x7FFFu + ((v.u >> 16) & 1u);   // RNE
  return (u16)(r >> 16);
}
__device__ __forceinline__ u32 cvtpk(float lo, float hi){
  u32 r; asm("v_cvt_pk_bf16_f32 %0, %1, %2" : "=v"(r) : "v"(lo), "v"(hi)); return r;
}
__device__ __forceinline__ void gll16(const void* g, void* l){
  __builtin_amdgcn_global_load_lds((__attribute__((address_space(1))) void*)g,
                                   (__attribute__((address_space(3))) void*)l, 16, 0, 0);
}

// ---------- convert_all: x->bf16 | Wa->bf16 | masters | bias fold | Wp transpose ----------
// grid: [0,4096) x | [4096,7168) Wa | 7168 masters | 7169-7171 bias | [7172,7428) Wp^T
__global__ __launch_bounds__(256) void convert_all(const float* __restrict__ x,
      const float* __restrict__ Wa, const float* __restrict__ ba, const float* __restrict__ Wp,
      const float* __restrict__ kc, const float* __restrict__ ke,
      const float* __restrict__ vc, const float* __restrict__ ve,
      u16* __restrict__ Xb, u16* __restrict__ Wab, u16* __restrict__ Mb,
      float* __restrict__ b2, u16* __restrict__ WpTb){
  __shared__ float SH[4160];           // 16640 B, aliased per branch
  const int bid = blockIdx.x, tid = threadIdx.x;
  if (bid < 4096){
    int i = bid*256 + tid;
    float4 v = ((const float4*)x)[i];
    ushort4 r; r.x=f2bf(v.x); r.y=f2bf(v.y); r.z=f2bf(v.z); r.w=f2bf(v.w);
    ((ushort4*)Xb)[i] = r;
  } else if (bid < 7168){
    int i = (bid-4096)*256 + tid;
    float4 v = ((const float4*)Wa)[i];
    ushort4 r; r.x=f2bf(v.x); r.y=f2bf(v.y); r.z=f2bf(v.z); r.w=f2bf(v.w);
    ((ushort4*)Wab)[i] = r;
  } else if (bid == 7168){
    // Mb: [0,2048) ke*SCLF [r][d] | [2048,4096) kc^T | [4096,6144) vc^T | [6144,8192) ve
    #pragma unroll
    for (int t=0;t<8;++t){
      int idx = t*256 + tid;
      Mb[idx] = f2bf(ke[idx]*SCLF);
      int d = idx>>5, r = idx&31;
      Mb[2048 + r*64 + d] = f2bf(kc[idx]);
      Mb[4096 + r*64 + d] = f2bf(vc[idx]);
      Mb[6144 + idx] = f2bf(ve[idx]);
    }
  } else if (bid < 7172){
    // bias fold (exact f32 math): part = bid-7169
    const int part = bid - 7169;
    float* BaL = SH;                   // [1024]
    float* W65 = SH + 1024;            // [32][65]
    *(float4*)&BaL[tid*4] = *(const float4*)&ba[part*1024 + tid*4];
    {
      const float* msrc = (part==0) ? ke : (part==1) ? kc : vc;
      #pragma unroll
      for (int i=0;i<8;++i){
        int idx = tid + i*256;
        float v = msrc[idx];
        int r, d;
        if (part == 0){ r = idx >> 6; d = idx & 63; }
        else          { d = idx >> 5; r = idx & 31; }
        W65[r*65 + d] = v;
      }
    }
    __syncthreads();
    const float scl = (part==0) ? SCLF : 1.f;
    #pragma unroll
    for (int t=0;t<2;++t){
      int l = tid + t*256;
      int hh = l >> 5, r = l & 31;
      float acc = 0.f;
      for (int d=0;d<64;++d) acc += BaL[hh*64 + d] * W65[r*65 + d];
      b2[part*512 + l] = acc * scl;
    }
  } else {
    // Wp transpose+cvt: WpTb[n][c] = f2bf(Wp[c][n]) in 64x64 tiles
    const int idx2 = bid - 7172;
    const int c0 = (idx2 & 15)*64, n0 = (idx2 >> 4)*64;
    float* tile = SH;                  // [64][65]
    int tx = tid & 63, ty = tid >> 6;
    #pragma unroll 4
    for (int k=0;k<16;++k){
      int r = 4*k + ty;
      tile[r*65 + tx] = Wp[(size_t)(c0+r)*1024 + n0 + tx];
    }
    __syncthreads();
    #pragma unroll 4
    for (int k=0;k<16;++k){
      int r = 4*k + ty;
      WpTb[(size_t)(n0+r)*1024 + c0 + tx] = f2bf(tile[tx*65 + r]);
    }
  }
}

// ---------- fold_gemms: y<48 qkv fold | y>=48 proj fold (MFMA mini-GEMMs, K=64) ----------
__global__ __launch_bounds__(256) void fold_gemms(const u16* __restrict__ Wab,
      const u16* __restrict__ Mb, const u16* __restrict__ WpTb,
      u16* __restrict__ Wt, u16* __restrict__ W2t){
  __shared__ u16 As[4096];   // [64][64 d]
  __shared__ u16 Bs[2048];   // [32 r][64 d]
  const int cc = blockIdx.x, y = blockIdx.y;
  const int tid = threadIdx.x, wv = tid>>6, ln = tid&63;
  const int lr = ln&15, g8 = (ln>>4)*8, gq = ln>>4;
  const int c0 = cc*64;
  const int lrow = ln>>3, lcol = (ln&7)*8;
  const bool qkv = (y < 48);
  const int ph = qkv ? y : (y - 48);
  const u16* A = qkv ? (Wab + (size_t)c0*3072 + ph*64) : (WpTb + (size_t)c0*1024 + ph*64);
  const u16* B = qkv ? (Mb + (ph>>4)*2048) : (Mb + 6144);
  const size_t astr = qkv ? 3072 : 1024;
  #pragma unroll
  for (int it=0;it<3;++it){
    int c3 = wv*3 + it;                  // 12 chunks: 0-7 A, 8-11 B
    if (c3 < 8) gll16(A + (size_t)(c3*8+lrow)*astr + lcol, &As[c3*512]);
    else { int bc = c3-8; gll16(B + (bc*8+lrow)*64 + lcol, &Bs[bc*512]); }
  }
  __syncthreads();
  f32x4 acc[2] = {};
  const int wr = (wv>>1)*32, wn = wv&1;
  #pragma unroll
  for (int ks=0;ks<2;++ks){
    bf16x8 bf = *(const bf16x8*)&Bs[(wn*16+lr)*64 + ks*32 + g8];
    #pragma unroll
    for (int mt=0;mt<2;++mt){
      bf16x8 af = *(const bf16x8*)&As[(wr+mt*16+lr)*64 + ks*32 + g8];
      acc[mt] = __builtin_amdgcn_mfma_f32_16x16x32_bf16(af, bf, acc[mt], 0,0,0);
    }
  }
  if (qkv){
    const int n = (ph>>4)*512 + (ph&15)*32 + wn*16 + lr;
    #pragma unroll
    for (int mt=0;mt<2;++mt){
      union { u16 s[4]; uint2 v; } pk;
      #pragma unroll
      for (int r=0;r<4;++r) pk.s[r] = f2bf(acc[mt][r]);
      *(uint2*)&Wt[(size_t)n*1024 + c0 + wr + mt*16 + 4*gq] = pk.v;
    }
  } else {
    const int col = ph*32 + wn*16 + lr;
    #pragma unroll
    for (int mt=0;mt<2;++mt)
      #pragma unroll
      for (int r=0;r<4;++r)
        W2t[(size_t)(c0 + wr + mt*16 + 4*gq + r)*512 + col] = f2bf(acc[mt][r]);
  }
}

// ---------- 64x128 bf16 GEMM (2-phase, gll16 both operands): C = A*Bt^T + bias ----------
template<typename OT>
__global__ __launch_bounds__(256) void gemm64(const u16* __restrict__ A, const u16* __restrict__ Bt,
        const float* __restrict__ bias, OT* __restrict__ C, u16* __restrict__ Vt,
        int M, int N, int K, int ldc){
  __shared__ u16 As[64*64];
  __shared__ u16 Bs[128*64];
  const int nwg = gridDim.x * gridDim.y;
  const int id  = blockIdx.x + gridDim.x * blockIdx.y;
  const int nid = (id & 7) * (nwg >> 3) + (id >> 3);   // nwg % 8 == 0
  const int bx = nid % gridDim.x, by = nid / gridDim.x;
  const int tid = threadIdx.x, wv = tid>>6, ln = tid&63;
  const int lr = ln&15, g8 = (ln>>4)*8;
  const int m0 = bx*64, n0 = by*128;
  const int wr = (wv>>1)*32, wc = (wv&1)*64;
  const int lrow = ln>>3, lcol = (ln&7)*8;
  f32x4 acc[2][4] = {};
  const int nk = K >> 6;
  for (int kt=0; kt<nk; ++kt){
    #pragma unroll
    for (int it=0; it<6; ++it){
      int chunk = wv*6 + it;
      if (chunk < 8){
        int row = chunk*8 + lrow;
        gll16(A + (size_t)(m0+row)*K + kt*64 + lcol, &As[chunk*512]);
      } else {
        int bc = chunk - 8;
        int row = bc*8 + lrow;
        gll16(Bt + (size_t)(n0+row)*K + kt*64 + lcol, &Bs[bc*512]);
      }
    }
    __syncthreads();
    #pragma unroll
    for (int ks=0; ks<2; ++ks){
      bf16x8 af[2], bfr[4];
      #pragma unroll
      for (int mt=0;mt<2;++mt) af[mt]  = *(const bf16x8*)&As[(wr+mt*16+lr)*64 + ks*32 + g8];
      #pragma unroll
      for (int nt=0;nt<4;++nt) bfr[nt] = *(const bf16x8*)&Bs[(wc+nt*16+lr)*64 + ks*32 + g8];
      #pragma unroll
      for (int mt=0;mt<2;++mt)
        #pragma unroll
        for (int nt=0;nt<4;++nt)
          acc[mt][nt] = __builtin_amdgcn_mfma_f32_16x16x32_bf16(af[mt], bfr[nt], acc[mt][nt], 0,0,0);
    }
    __syncthreads();
  }
  if (Vt && n0 >= 1024){
    #pragma unroll
    for (int mt=0;mt<2;++mt){
      int row0 = m0 + wr + mt*16 + 4*(ln>>4);
      int tin  = row0 & 2047;
      int p0 = 4*((tin>>4)&1) + 8*((tin>>2)&3) + 32*(tin>>5);
      size_t vbase = (size_t)(row0 >> 11) * 512;
      #pragma unroll
      for (int nt=0;nt<4;++nt){
        int col = n0 + wc + nt*16 + lr;
        float bv = bias[col];
        int nlat = col - 1024;
        union { u16 s[4]; uint2 v; } pk;
        #pragma unroll
        for (int r=0;r<4;++r) pk.s[r] = f2bf(acc[mt][nt][r] + bv);
        *(uint2*)&Vt[(vbase + nlat)*2048 + p0] = pk.v;
      }
    }
  } else {
    #pragma unroll
    for (int mt=0;mt<2;++mt){
      int row = m0 + wr + mt*16 + 4*(ln>>4);
      #pragma unroll
      for (int nt=0;nt<4;++nt){
        int col = n0 + wc + nt*16 + lr;
        float bv = bias[col];
        #pragma unroll
        for (int r=0;r<4;++r){
          float v = acc[mt][nt][r] + bv;
          if constexpr (sizeof(OT) == 2) C[(size_t)(row+r)*ldc + col] = f2bf(v);
          else                           C[(size_t)(row+r)*ldc + col] = v;
        }
      }
    }
  }
}

// ---------- causal flash attention, rank-32 latent, 32 q-rows per wave ----------
// 256 thr = 2 subgroups x 2 waves; wave owns 32 q (2 fragments); kt ≡ sg (mod 2).
// Each K/V LDS fragment read feeds 2 MFMAs -> LDS reads halved vs 16q/wave.
__global__ __launch_bounds__(256, 4) void attn_fwd(const u16* __restrict__ QKV,
            const u16* __restrict__ Vt, u16* __restrict__ Out){
  const int bh = blockIdx.x;
  const int qt = 31 - blockIdx.y;          // LPT
  const int b = bh >> 4, h = bh & 15;
  const int tid = threadIdx.x, wv = tid>>6, ln = tid&63;
  const int sg = wv>>1, wvL = wv&1;
  const int lr = ln&15, gq = ln>>4;
  __shared__ __align__(16) char SMEM[32768];
  u16* KB0 = (u16*)SMEM           + (sg*2    )*2048;   // [64 kv][32 d] 4KB
  u16* KB1 = (u16*)SMEM           + (sg*2 + 1)*2048;
  u16* VB0 = (u16*)(SMEM + 16384) + (sg*2    )*2048;   // [32 r][64 kv-perm] 4KB
  u16* VB1 = (u16*)(SMEM + 16384) + (sg*2 + 1)*2048;
  const int q0 = qt*64;
  const size_t base = (size_t)(b*2048) * 1536;
  const u16* qrowA = QKV + base + (size_t)(q0 + wvL*32 + lr)*1536 + h*32;
  bf16x8 qfA = *(const bf16x8*)(qrowA + gq*8);
  bf16x8 qfB = *(const bf16x8*)(qrowA + (size_t)16*1536 + gq*8);
  const int qgA = q0 + wvL*32 + lr, qgB = qgA + 16;
  f32x4 oA0 = {}, oA1 = {}, oB0 = {}, oB1 = {};
  float lA = 0.f, lB = 0.f;
  const u16* ksrc = QKV + base + 512 + h*32;
  const u16* vsrc = Vt + (size_t)(bh*32)*2048;

  // staging: 128 threads/subgroup, 2 gll16 each for K and V (rows +32 / +16 share swizzle)
  const int ci = wvL*64 + ln;
  const int rK = ci>>2, cK = 8*((ci&3) ^ (rK&3));
  const int rV = ci>>3, cV = 8*((ci&7) ^ (rV&7));

  int offK[4], offV[2][2];
  #pragma unroll
  for (int nt=0;nt<4;++nt)
    offK[nt] = (nt*16+lr)*64 + ((gq*16) ^ ((lr&3)<<4));
  #pragma unroll
  for (int dt=0;dt<2;++dt)
    #pragma unroll
    for (int c=0;c<2;++c)
      offV[dt][c] = (dt*16+lr)*128 + ((c*64 + gq*16) ^ ((lr&7)<<4));

  if (sg <= qt){
    gll16(ksrc + (size_t)(sg*64 + rK)*1536 + cK,      KB0 + wvL*512);
    gll16(ksrc + (size_t)(sg*64 + 32 + rK)*1536 + cK, KB0 + 1024 + wvL*512);
    gll16(vsrc + (size_t)rV*2048 + sg*64 + cV,        VB0 + wvL*512);
    gll16(vsrc + (size_t)(16+rV)*2048 + sg*64 + cV,   VB0 + 1024 + wvL*512);
  }
  __syncthreads();
  const u16* kpa = ksrc + (size_t)(sg*64 + 128 + rK)*1536 + cK;
  const u16* kpb = ksrc + (size_t)(sg*64 + 160 + rK)*1536 + cK;
  const u16* vpa = vsrc + (size_t)rV*2048 + sg*64 + 128 + cV;
  const u16* vpb = vsrc + (size_t)(16+rV)*2048 + sg*64 + 128 + cV;
  const size_t KSTEP = (size_t)128*1536;

  #define ABODY(II, KBC, VBC, KBN, VBN) do { \
    const int kt = 2*(II) + sg; \
    if (kt + 2 <= qt){ \
      gll16(kpa, (KBN) + wvL*512); \
      gll16(kpb, (KBN) + 1024 + wvL*512); \
      gll16(vpa, (VBN) + wvL*512); \
      gll16(vpb, (VBN) + 1024 + wvL*512); \
      kpa += KSTEP; kpb += KSTEP; vpa += 128; vpb += 128; \
    } \
    if (kt <= qt){ \
      f32x4 sA[4] = {}, sB[4] = {}; \
      __builtin_amdgcn_s_setprio(1); \
      _Pragma("unroll") for (int nt=0;nt<4;++nt){ \
        bf16x8 k0 = *(const bf16x8*)((const char*)(KBC) + offK[nt]); \
        sA[nt] = __builtin_amdgcn_mfma_f32_16x16x32_bf16(k0, qfA, sA[nt], 0,0,0); \
        sB[nt] = __builtin_amdgcn_mfma_f32_16x16x32_bf16(k0, qfB, sB[nt], 0,0,0); \
      } \
      __builtin_amdgcn_s_setprio(0); \
      if (kt == qt){ \
        const int kv0 = kt*64; \
        _Pragma("unroll") for (int nt=0;nt<4;++nt) \
        _Pragma("unroll") for (int r=0;r<4;++r){ \
          int k = kv0 + nt*16 + 4*gq + r; \
          if (k > qgA) sA[nt][r] = -1e30f; \
          if (k > qgB) sB[nt][r] = -1e30f; \
        } \
      } \
      union { u32 u[4]; bf16x8 v; } paA0, paA1, paB0, paB1; \
      { \
        float p0,p1,p2,p3,p4,p5,p6,p7; \
        p0=__builtin_amdgcn_exp2f(sA[0][0]); p1=__builtin_amdgcn_exp2f(sA[0][1]); \
        p2=__builtin_amdgcn_exp2f(sA[0][2]); p3=__builtin_amdgcn_exp2f(sA[0][3]); \
        p4=__builtin_amdgcn_exp2f(sA[1][0]); p5=__builtin_amdgcn_exp2f(sA[1][1]); \
        p6=__builtin_amdgcn_exp2f(sA[1][2]); p7=__builtin_amdgcn_exp2f(sA[1][3]); \
        lA += ((p0+p1)+(p2+p3)) + ((p4+p5)+(p6+p7)); \
        paA0.u[0]=cvtpk(p0,p1); paA0.u[1]=cvtpk(p2,p3); paA0.u[2]=cvtpk(p4,p5); paA0.u[3]=cvtpk(p6,p7); \
        p0=__builtin_amdgcn_exp2f(sA[2][0]); p1=__builtin_amdgcn_exp2f(sA[2][1]); \
        p2=__builtin_amdgcn_exp2f(sA[2][2]); p3=__builtin_amdgcn_exp2f(sA[2][3]); \
        p4=__builtin_amdgcn_exp2f(sA[3][0]); p5=__builtin_amdgcn_exp2f(sA[3][1]); \
        p6=__builtin_amdgcn_exp2f(sA[3][2]); p7=__builtin_amdgcn_exp2f(sA[3][3]); \
        lA += ((p0+p1)+(p2+p3)) + ((p4+p5)+(p6+p7)); \
        paA1.u[0]=cvtpk(p0,p1); paA1.u[1]=cvtpk(p2,p3); paA1.u[2]=cvtpk(p4,p5); paA1.u[3]=cvtpk(p6,p7); \
        p0=__builtin_amdgcn_exp2f(sB[0][0]); p1=__builtin_amdgcn_exp2f(sB[0][1]); \
        p2=__builtin_amdgcn_exp2f(sB[0][2]); p3=__builtin_amdgcn_exp2f(sB[0][3]); \
        p4=__builtin_amdgcn_exp2f(sB[1][0]); p5=__builtin_amdgcn_exp2f(sB[1][1]); \
        p6=__builtin_amdgcn_exp2f(sB[1][2]); p7=__builtin_amdgcn_exp2f(sB[1][3]); \
        lB += ((p0+p1)+(p2+p3)) + ((p4+p5)+(p6+p7)); \
        paB0.u[0]=cvtpk(p0,p1); paB0.u[1]=cvtpk(p2,p3); paB0.u[2]=cvtpk(p4,p5); paB0.u[3]=cvtpk(p6,p7); \
        p0=__builtin_amdgcn_exp2f(sB[2][0]); p1=__builtin_amdgcn_exp2f(sB[2][1]); \
        p2=__builtin_amdgcn_exp2f(sB[2][2]); p3=__builtin_amdgcn_exp2f(sB[2][3]); \
        p4=__builtin_amdgcn_exp2f(sB[3][0]); p5=__builtin_amdgcn_exp2f(sB[3][1]); \
        p6=__builtin_amdgcn_exp2f(sB[3][2]); p7=__builtin_amdgcn_exp2f(sB[3][3]); \
        lB += ((p0+p1)+(p2+p3)) + ((p4+p5)+(p6+p7)); \
        paB1.u[0]=cvtpk(p0,p1); paB1.u[1]=cvtpk(p2,p3); paB1.u[2]=cvtpk(p4,p5); paB1.u[3]=cvtpk(p6,p7); \
      } \
      __builtin_amdgcn_s_setprio(1); \
      { \
        bf16x8 v00 = *(const bf16x8*)((const char*)(VBC) + offV[0][0]); \
        bf16x8 v10 = *(const bf16x8*)((const char*)(VBC) + offV[1][0]); \
        bf16x8 v01 = *(const bf16x8*)((const char*)(VBC) + offV[0][1]); \
        bf16x8 v11 = *(const bf16x8*)((const char*)(VBC) + offV[1][1]); \
        oA0 = __builtin_amdgcn_mfma_f32_16x16x32_bf16(paA0.v, v00, oA0, 0,0,0); \
        oA1 = __builtin_amdgcn_mfma_f32_16x16x32_bf16(paA0.v, v10, oA1, 0,0,0); \
        oB0 = __builtin_amdgcn_mfma_f32_16x16x32_bf16(paB0.v, v00, oB0, 0,0,0); \
        oB1 = __builtin_amdgcn_mfma_f32_16x16x32_bf16(paB0.v, v10, oB1, 0,0,0); \
        oA0 = __builtin_amdgcn_mfma_f32_16x16x32_bf16(paA1.v, v01, oA0, 0,0,0); \
        oA1 = __builtin_amdgcn_mfma_f32_16x16x32_bf16(paA1.v, v11, oA1, 0,0,0); \
        oB0 = __builtin_amdgcn_mfma_f32_16x16x32_bf16(paB1.v, v01, oB0, 0,0,0); \
        oB1 = __builtin_amdgcn_mfma_f32_16x16x32_bf16(paB1.v, v11, oB1, 0,0,0); \
      } \
      __builtin_amdgcn_s_setprio(0); \
    } \
    __syncthreads(); \
  } while(0)

  const int nmax = (qt + 2) >> 1;
  const int jmax = (nmax + 1) >> 1;
  for (int j = 0; j < jmax; ++j){
    ABODY(2*j,   KB0, VB0, KB1, VB1);
    ABODY(2*j+1, KB1, VB1, KB0, VB0);
  }
  lA += __shfl_xor(lA, 16); lA += __shfl_xor(lA, 32);
  lB += __shfl_xor(lB, 16); lB += __shfl_xor(lB, 32);

  // ---- in-LDS merge of the two partial (unnormalized) results ----
  float* MO = (float*)SMEM;               // [64][34] padded
  float* ML = (float*)(SMEM + 12288);     // l[64]
  if (sg == 1){
    #pragma unroll
    for (int r=0;r<4;++r){
      int rowA = wvL*32 + 4*gq + r;
      MO[rowA*34 + lr]            = oA0[r];
      MO[rowA*34 + 16 + lr]       = oA1[r];
      MO[(rowA+16)*34 + lr]       = oB0[r];
      MO[(rowA+16)*34 + 16 + lr]  = oB1[r];
    }
    if (gq == 0){ ML[wvL*32 + lr] = lA; ML[wvL*32 + 16 + lr] = lB; }
  }
  __syncthreads();
  if (sg == 0){
    float lSA = lA + ML[wvL*32 + lr];
    float lSB = lB + ML[wvL*32 + 16 + lr];
    float lA_o[4], lB_o[4];
    #pragma unroll
    for (int r=0;r<4;++r){ lA_o[r] = __shfl(lSA, 4*gq + r); lB_o[r] = __shfl(lSB, 4*gq + r); }
    #pragma unroll
    for (int r=0;r<4;++r){
      int rowA = wvL*32 + 4*gq + r;
      float vA0 = (oA0[r] + MO[rowA*34 + lr])           / lA_o[r];
      float vA1 = (oA1[r] + MO[rowA*34 + 16 + lr])      / lA_o[r];
      float vB0 = (oB0[r] + MO[(rowA+16)*34 + lr])      / lB_o[r];
      float vB1 = (oB1[r] + MO[(rowA+16)*34 + 16 + lr]) / lB_o[r];
      size_t obA = (size_t)(b*2048 + q0 + rowA)*512 + h*32;
      Out[obA + lr]      = f2bf(vA0);
      Out[obA + 16 + lr] = f2bf(vA1);
      size_t obB = obA + (size_t)16*512;
      Out[obB + lr]      = f2bf(vB0);
      Out[obB + 16 + lr] = f2bf(vB1);
    }
  }
}

// ---------- workspace layout (bytes) ----------
#define WS_B2   0u                                   // 1536*4
#define WS_WT   8192u                                // 1536*1024*2 = 3145728
#define WS_W2T  (WS_WT + 3145728u)                   // 1024*512*2  = 1048576
#define WS_XB   (WS_W2T + 1048576u)                  // 4096*1024*2 = 8388608
#define WS_QKV  (WS_XB + 8388608u)                   // 4096*1536*2 = 12582912
#define WS_VT   (WS_QKV + 12582912u)                 // 1024*2048*2 = 4194304
#define WS_ATT  (WS_VT + 4194304u)                   // 4096*512*2  = 4194304
#define WS_WAB  (WS_ATT + 4194304u)                  // 1024*3072*2 = 6291456
#define WS_WPT  (WS_WAB + 6291456u)                  // 1024*1024*2 = 2097152
#define WS_MB   (WS_WPT + 2097152u)                  // 8192*2 = 16384

extern "C" void kernel_launch(void* const* d_in, const int* in_sizes, int n_in,
                              void* d_out, int out_size, void* d_ws, size_t ws_size,
                              hipStream_t stream) {
  const float* x  = (const float*)d_in[0];
  const float* Wa = (const float*)d_in[1];
  const float* ba = (const float*)d_in[2];
  const float* Wp = (const float*)d_in[3];
  const float* bp = (const float*)d_in[4];
  const float* kc = (const float*)d_in[5];
  const float* ke = (const float*)d_in[6];
  const float* vc = (const float*)d_in[7];
  const float* ve = (const float*)d_in[8];
  float* out = (float*)d_out;
  char* ws = (char*)d_ws;
  float* b2  = (float*)(ws + WS_B2);
  u16* Wt    = (u16*)(ws + WS_WT);
  u16* W2t   = (u16*)(ws + WS_W2T);
  u16* Xb    = (u16*)(ws + WS_XB);
  u16* QKVb  = (u16*)(ws + WS_QKV);
  u16* Vt    = (u16*)(ws + WS_VT);
  u16* Att   = (u16*)(ws + WS_ATT);
  u16* Wab   = (u16*)(ws + WS_WAB);
  u16* WpTb  = (u16*)(ws + WS_WPT);
  u16* Mb    = (u16*)(ws + WS_MB);

  convert_all<<<7428, 256, 0, stream>>>(x, Wa, ba, Wp, kc, ke, vc, ve, Xb, Wab, Mb, b2, WpTb);
  fold_gemms<<<dim3(16,64), 256, 0, stream>>>(Wab, Mb, WpTb, Wt, W2t);
  gemm64<u16><<<dim3(64,12), 256, 0, stream>>>(Xb, Wt, b2, QKVb, Vt, 4096, 1536, 1024, 1536);
  attn_fwd<<<dim3(32,32), 256, 0, stream>>>(QKVb, Vt, Att);
  gemm64<float><<<dim3(64,8), 256, 0, stream>>>(Att, W2t, bp, out, (u16*)nullptr, 4096, 1024, 512, 1024);
}

// Round 16
// 73.089 us; speedup vs baseline: 1.2536x; 1.0956x over previous
//
#include <hip/hip_runtime.h>
#include <cstddef>

typedef __attribute__((ext_vector_type(8))) __bf16 bf16x8;
typedef __attribute__((ext_vector_type(4))) float f32x4;
typedef unsigned short u16;
typedef unsigned int   u32;

#define SCLF (0.125f * 1.44269504f)   // softmax scale * log2(e), baked into q' master weights

// ---------- helpers ----------
__device__ __forceinline__ u16 f2bf(float f){
  union { float f; u32 u; } v; v.f = f;
  u32 r = v.u + 0x7FFFu + ((v.u >> 16) & 1u);   // RNE
  return (u16)(r >> 16);
}
__device__ __forceinline__ u32 cvtpk(float lo, float hi){
  u32 r; asm("v_cvt_pk_bf16_f32 %0, %1, %2" : "=v"(r) : "v"(lo), "v"(hi)); return r;
}
__device__ __forceinline__ void gll16(const void* g, void* l){
  __builtin_amdgcn_global_load_lds((__attribute__((address_space(1))) void*)g,
                                   (__attribute__((address_space(3))) void*)l, 16, 0, 0);
}

// ---------- convert_all: x->bf16 | Wa->bf16 | masters | bias fold | Wp transpose ----------
// grid: [0,4096) x | [4096,7168) Wa | 7168 masters | 7169-7171 bias | [7172,7428) Wp^T
__global__ __launch_bounds__(256) void convert_all(const float* __restrict__ x,
      const float* __restrict__ Wa, const float* __restrict__ ba, const float* __restrict__ Wp,
      const float* __restrict__ kc, const float* __restrict__ ke,
      const float* __restrict__ vc, const float* __restrict__ ve,
      u16* __restrict__ Xb, u16* __restrict__ Wab, u16* __restrict__ Mb,
      float* __restrict__ b2, u16* __restrict__ WpTb){
  __shared__ float SH[4160];           // 16640 B, aliased per branch
  const int bid = blockIdx.x, tid = threadIdx.x;
  if (bid < 4096){
    int i = bid*256 + tid;
    float4 v = ((const float4*)x)[i];
    uint2 r; r.x = cvtpk(v.x, v.y); r.y = cvtpk(v.z, v.w);
    ((uint2*)Xb)[i] = r;
  } else if (bid < 7168){
    int i = (bid-4096)*256 + tid;
    float4 v = ((const float4*)Wa)[i];
    uint2 r; r.x = cvtpk(v.x, v.y); r.y = cvtpk(v.z, v.w);
    ((uint2*)Wab)[i] = r;
  } else if (bid == 7168){
    // Mb: [0,2048) ke*SCLF [r][d] | [2048,4096) kc^T | [4096,6144) vc^T | [6144,8192) ve
    #pragma unroll
    for (int t=0;t<8;++t){
      int idx = t*256 + tid;
      Mb[idx] = f2bf(ke[idx]*SCLF);
      int d = idx>>5, r = idx&31;
      Mb[2048 + r*64 + d] = f2bf(kc[idx]);
      Mb[4096 + r*64 + d] = f2bf(vc[idx]);
      Mb[6144 + idx] = f2bf(ve[idx]);
    }
  } else if (bid < 7172){
    // bias fold (exact f32 math): part = bid-7169
    const int part = bid - 7169;
    float* BaL = SH;                   // [1024]
    float* W65 = SH + 1024;            // [32][65]
    *(float4*)&BaL[tid*4] = *(const float4*)&ba[part*1024 + tid*4];
    {
      const float* msrc = (part==0) ? ke : (part==1) ? kc : vc;
      #pragma unroll
      for (int i=0;i<8;++i){
        int idx = tid + i*256;
        float v = msrc[idx];
        int r, d;
        if (part == 0){ r = idx >> 6; d = idx & 63; }
        else          { d = idx >> 5; r = idx & 31; }
        W65[r*65 + d] = v;
      }
    }
    __syncthreads();
    const float scl = (part==0) ? SCLF : 1.f;
    #pragma unroll
    for (int t=0;t<2;++t){
      int l = tid + t*256;
      int hh = l >> 5, r = l & 31;
      float acc = 0.f;
      for (int d=0;d<64;++d) acc += BaL[hh*64 + d] * W65[r*65 + d];
      b2[part*512 + l] = acc * scl;
    }
  } else {
    // Wp transpose+cvt: WpTb[n][c] = f2bf(Wp[c][n]) in 64x64 tiles
    const int idx2 = bid - 7172;
    const int c0 = (idx2 & 15)*64, n0 = (idx2 >> 4)*64;
    float* tile = SH;                  // [64][65]
    int tx = tid & 63, ty = tid >> 6;
    #pragma unroll 4
    for (int k=0;k<16;++k){
      int r = 4*k + ty;
      tile[r*65 + tx] = Wp[(size_t)(c0+r)*1024 + n0 + tx];
    }
    __syncthreads();
    #pragma unroll 4
    for (int k=0;k<16;++k){
      int r = 4*k + ty;
      WpTb[(size_t)(n0+r)*1024 + c0 + tx] = f2bf(tile[tx*65 + r]);
    }
  }
}

// ---------- fold_gemms: y<48 qkv fold | y>=48 proj fold (MFMA mini-GEMMs, K=64) ----------
// T2 both-sides swizzle: pre-swizzled source col + XOR'd fragment reads (conflict-free).
__global__ __launch_bounds__(256) void fold_gemms(const u16* __restrict__ Wab,
      const u16* __restrict__ Mb, const u16* __restrict__ WpTb,
      u16* __restrict__ Wt, u16* __restrict__ W2t){
  __shared__ u16 As[4096];   // [64][64 d] swizzled
  __shared__ u16 Bs[2048];   // [32 r][64 d] swizzled
  const int cc = blockIdx.x, y = blockIdx.y;
  const int tid = threadIdx.x, wv = tid>>6, ln = tid&63;
  const int lr = ln&15, g8 = (ln>>4)*8, gq = ln>>4;
  const int c0 = cc*64;
  const int lrow = ln>>3, lcol = ((ln&7) ^ lrow)*8;   // pre-swizzled source col
  const int swz = (lr&7)*8;
  const bool qkv = (y < 48);
  const int ph = qkv ? y : (y - 48);
  const u16* A = qkv ? (Wab + (size_t)c0*3072 + ph*64) : (WpTb + (size_t)c0*1024 + ph*64);
  const u16* B = qkv ? (Mb + (ph>>4)*2048) : (Mb + 6144);
  const size_t astr = qkv ? 3072 : 1024;
  #pragma unroll
  for (int it=0;it<3;++it){
    int c3 = wv*3 + it;                  // 12 chunks: 0-7 A, 8-11 B
    if (c3 < 8) gll16(A + (size_t)(c3*8+lrow)*astr + lcol, &As[c3*512]);
    else { int bc = c3-8; gll16(B + (bc*8+lrow)*64 + lcol, &Bs[bc*512]); }
  }
  __syncthreads();
  f32x4 acc[2] = {};
  const int wr = (wv>>1)*32, wn = wv&1;
  #pragma unroll
  for (int ks=0;ks<2;++ks){
    int off = (ks*32 + g8) ^ swz;
    bf16x8 bf = *(const bf16x8*)&Bs[(wn*16+lr)*64 + off];
    #pragma unroll
    for (int mt=0;mt<2;++mt){
      bf16x8 af = *(const bf16x8*)&As[(wr+mt*16+lr)*64 + off];
      acc[mt] = __builtin_amdgcn_mfma_f32_16x16x32_bf16(af, bf, acc[mt], 0,0,0);
    }
  }
  if (qkv){
    const int n = (ph>>4)*512 + (ph&15)*32 + wn*16 + lr;
    #pragma unroll
    for (int mt=0;mt<2;++mt){
      union { u16 s[4]; uint2 v; } pk;
      #pragma unroll
      for (int r=0;r<4;++r) pk.s[r] = f2bf(acc[mt][r]);
      *(uint2*)&Wt[(size_t)n*1024 + c0 + wr + mt*16 + 4*gq] = pk.v;
    }
  } else {
    const int col = ph*32 + wn*16 + lr;
    #pragma unroll
    for (int mt=0;mt<2;++mt)
      #pragma unroll
      for (int r=0;r<4;++r)
        W2t[(size_t)(c0 + wr + mt*16 + 4*gq + r)*512 + col] = f2bf(acc[mt][r]);
  }
}

// ---------- 64x128 bf16 GEMM (2-phase, gll16, T2-swizzled LDS): C = A*Bt^T + bias ----------
template<typename OT>
__global__ __launch_bounds__(256) void gemm64(const u16* __restrict__ A, const u16* __restrict__ Bt,
        const float* __restrict__ bias, OT* __restrict__ C, u16* __restrict__ Vt,
        int M, int N, int K, int ldc){
  __shared__ u16 As[64*64];
  __shared__ u16 Bs[128*64];
  const int nwg = gridDim.x * gridDim.y;
  const int id  = blockIdx.x + gridDim.x * blockIdx.y;
  const int nid = (id & 7) * (nwg >> 3) + (id >> 3);   // nwg % 8 == 0
  const int bx = nid % gridDim.x, by = nid / gridDim.x;
  const int tid = threadIdx.x, wv = tid>>6, ln = tid&63;
  const int lr = ln&15, g8 = (ln>>4)*8;
  const int m0 = bx*64, n0 = by*128;
  const int wr = (wv>>1)*32, wc = (wv&1)*64;
  const int lrow = ln>>3, lcol = ((ln&7) ^ lrow)*8;   // pre-swizzled source col
  const int swz = (lr&7)*8;
  f32x4 acc[2][4] = {};
  const int nk = K >> 6;
  for (int kt=0; kt<nk; ++kt){
    #pragma unroll
    for (int it=0; it<6; ++it){
      int chunk = wv*6 + it;
      if (chunk < 8){
        int row = chunk*8 + lrow;
        gll16(A + (size_t)(m0+row)*K + kt*64 + lcol, &As[chunk*512]);
      } else {
        int bc = chunk - 8;
        int row = bc*8 + lrow;
        gll16(Bt + (size_t)(n0+row)*K + kt*64 + lcol, &Bs[bc*512]);
      }
    }
    __syncthreads();
    #pragma unroll
    for (int ks=0; ks<2; ++ks){
      int off = (ks*32 + g8) ^ swz;
      bf16x8 af[2], bfr[4];
      #pragma unroll
      for (int mt=0;mt<2;++mt) af[mt]  = *(const bf16x8*)&As[(wr+mt*16+lr)*64 + off];
      #pragma unroll
      for (int nt=0;nt<4;++nt) bfr[nt] = *(const bf16x8*)&Bs[(wc+nt*16+lr)*64 + off];
      #pragma unroll
      for (int mt=0;mt<2;++mt)
        #pragma unroll
        for (int nt=0;nt<4;++nt)
          acc[mt][nt] = __builtin_amdgcn_mfma_f32_16x16x32_bf16(af[mt], bfr[nt], acc[mt][nt], 0,0,0);
    }
    __syncthreads();
  }
  if (Vt && n0 >= 1024){
    #pragma unroll
    for (int mt=0;mt<2;++mt){
      int row0 = m0 + wr + mt*16 + 4*(ln>>4);
      int tin  = row0 & 2047;
      int p0 = 4*((tin>>4)&1) + 8*((tin>>2)&3) + 32*(tin>>5);
      size_t vbase = (size_t)(row0 >> 11) * 512;
      #pragma unroll
      for (int nt=0;nt<4;++nt){
        int col = n0 + wc + nt*16 + lr;
        float bv = bias[col];
        int nlat = col - 1024;
        union { u16 s[4]; uint2 v; } pk;
        #pragma unroll
        for (int r=0;r<4;++r) pk.s[r] = f2bf(acc[mt][nt][r] + bv);
        *(uint2*)&Vt[(vbase + nlat)*2048 + p0] = pk.v;
      }
    }
  } else {
    #pragma unroll
    for (int mt=0;mt<2;++mt){
      int row = m0 + wr + mt*16 + 4*(ln>>4);
      #pragma unroll
      for (int nt=0;nt<4;++nt){
        int col = n0 + wc + nt*16 + lr;
        float bv = bias[col];
        #pragma unroll
        for (int r=0;r<4;++r){
          float v = acc[mt][nt][r] + bv;
          if constexpr (sizeof(OT) == 2) C[(size_t)(row+r)*ldc + col] = f2bf(v);
          else                           C[(size_t)(row+r)*ldc + col] = v;
        }
      }
    }
  }
}

// ---------- causal flash attention, rank-32 latent, 32 q-rows per wave ----------
// 256 thr = 2 subgroups x 2 waves; wave owns 32 q (2 fragments); kt ≡ sg (mod 2).
// Balanced qt map: co-resident {y,y+8,y+16,y+24} -> qt sums 62 on every CU.
__global__ __launch_bounds__(256, 4) void attn_fwd(const u16* __restrict__ QKV,
            const u16* __restrict__ Vt, u16* __restrict__ Out){
  const int bh = blockIdx.x;
  const int y = blockIdx.y;
  const int qt = (y < 8) ? y : (y < 16) ? 23 - y : (y < 24) ? y : 55 - y;
  const int b = bh >> 4, h = bh & 15;
  const int tid = threadIdx.x, wv = tid>>6, ln = tid&63;
  const int sg = wv>>1, wvL = wv&1;
  const int lr = ln&15, gq = ln>>4;
  __shared__ __align__(16) char SMEM[32768];
  u16* KB0 = (u16*)SMEM           + (sg*2    )*2048;   // [64 kv][32 d] 4KB
  u16* KB1 = (u16*)SMEM           + (sg*2 + 1)*2048;
  u16* VB0 = (u16*)(SMEM + 16384) + (sg*2    )*2048;   // [32 r][64 kv-perm] 4KB
  u16* VB1 = (u16*)(SMEM + 16384) + (sg*2 + 1)*2048;
  const int q0 = qt*64;
  const size_t base = (size_t)(b*2048) * 1536;
  const u16* qrowA = QKV + base + (size_t)(q0 + wvL*32 + lr)*1536 + h*32;
  bf16x8 qfA = *(const bf16x8*)(qrowA + gq*8);
  bf16x8 qfB = *(const bf16x8*)(qrowA + (size_t)16*1536 + gq*8);
  const int qgA = q0 + wvL*32 + lr, qgB = qgA + 16;
  f32x4 oA0 = {}, oA1 = {}, oB0 = {}, oB1 = {};
  float lA = 0.f, lB = 0.f;
  const u16* ksrc = QKV + base + 512 + h*32;
  const u16* vsrc = Vt + (size_t)(bh*32)*2048;

  const int ci = wvL*64 + ln;
  const int rK = ci>>2, cK = 8*((ci&3) ^ (rK&3));
  const int rV = ci>>3, cV = 8*((ci&7) ^ (rV&7));

  int offK[4], offV[2][2];
  #pragma unroll
  for (int nt=0;nt<4;++nt)
    offK[nt] = (nt*16+lr)*64 + ((gq*16) ^ ((lr&3)<<4));
  #pragma unroll
  for (int dt=0;dt<2;++dt)
    #pragma unroll
    for (int c=0;c<2;++c)
      offV[dt][c] = (dt*16+lr)*128 + ((c*64 + gq*16) ^ ((lr&7)<<4));

  if (sg <= qt){
    gll16(ksrc + (size_t)(sg*64 + rK)*1536 + cK,      KB0 + wvL*512);
    gll16(ksrc + (size_t)(sg*64 + 32 + rK)*1536 + cK, KB0 + 1024 + wvL*512);
    gll16(vsrc + (size_t)rV*2048 + sg*64 + cV,        VB0 + wvL*512);
    gll16(vsrc + (size_t)(16+rV)*2048 + sg*64 + cV,   VB0 + 1024 + wvL*512);
  }
  __syncthreads();
  const u16* kpa = ksrc + (size_t)(sg*64 + 128 + rK)*1536 + cK;
  const u16* kpb = ksrc + (size_t)(sg*64 + 160 + rK)*1536 + cK;
  const u16* vpa = vsrc + (size_t)rV*2048 + sg*64 + 128 + cV;
  const u16* vpb = vsrc + (size_t)(16+rV)*2048 + sg*64 + 128 + cV;
  const size_t KSTEP = (size_t)128*1536;

  #define ABODY(II, KBC, VBC, KBN, VBN) do { \
    const int kt = 2*(II) + sg; \
    if (kt + 2 <= qt){ \
      gll16(kpa, (KBN) + wvL*512); \
      gll16(kpb, (KBN) + 1024 + wvL*512); \
      gll16(vpa, (VBN) + wvL*512); \
      gll16(vpb, (VBN) + 1024 + wvL*512); \
      kpa += KSTEP; kpb += KSTEP; vpa += 128; vpb += 128; \
    } \
    if (kt <= qt){ \
      f32x4 sA[4] = {}, sB[4] = {}; \
      __builtin_amdgcn_s_setprio(1); \
      _Pragma("unroll") for (int nt=0;nt<4;++nt){ \
        bf16x8 k0 = *(const bf16x8*)((const char*)(KBC) + offK[nt]); \
        sA[nt] = __builtin_amdgcn_mfma_f32_16x16x32_bf16(k0, qfA, sA[nt], 0,0,0); \
        sB[nt] = __builtin_amdgcn_mfma_f32_16x16x32_bf16(k0, qfB, sB[nt], 0,0,0); \
      } \
      __builtin_amdgcn_s_setprio(0); \
      if (kt == qt){ \
        const int kv0 = kt*64; \
        _Pragma("unroll") for (int nt=0;nt<4;++nt) \
        _Pragma("unroll") for (int r=0;r<4;++r){ \
          int k = kv0 + nt*16 + 4*gq + r; \
          if (k > qgA) sA[nt][r] = -1e30f; \
          if (k > qgB) sB[nt][r] = -1e30f; \
        } \
      } \
      union { u32 u[4]; bf16x8 v; } paA0, paA1, paB0, paB1; \
      { \
        float p0,p1,p2,p3,p4,p5,p6,p7; \
        p0=__builtin_amdgcn_exp2f(sA[0][0]); p1=__builtin_amdgcn_exp2f(sA[0][1]); \
        p2=__builtin_amdgcn_exp2f(sA[0][2]); p3=__builtin_amdgcn_exp2f(sA[0][3]); \
        p4=__builtin_amdgcn_exp2f(sA[1][0]); p5=__builtin_amdgcn_exp2f(sA[1][1]); \
        p6=__builtin_amdgcn_exp2f(sA[1][2]); p7=__builtin_amdgcn_exp2f(sA[1][3]); \
        lA += ((p0+p1)+(p2+p3)) + ((p4+p5)+(p6+p7)); \
        paA0.u[0]=cvtpk(p0,p1); paA0.u[1]=cvtpk(p2,p3); paA0.u[2]=cvtpk(p4,p5); paA0.u[3]=cvtpk(p6,p7); \
        p0=__builtin_amdgcn_exp2f(sA[2][0]); p1=__builtin_amdgcn_exp2f(sA[2][1]); \
        p2=__builtin_amdgcn_exp2f(sA[2][2]); p3=__builtin_amdgcn_exp2f(sA[2][3]); \
        p4=__builtin_amdgcn_exp2f(sA[3][0]); p5=__builtin_amdgcn_exp2f(sA[3][1]); \
        p6=__builtin_amdgcn_exp2f(sA[3][2]); p7=__builtin_amdgcn_exp2f(sA[3][3]); \
        lA += ((p0+p1)+(p2+p3)) + ((p4+p5)+(p6+p7)); \
        paA1.u[0]=cvtpk(p0,p1); paA1.u[1]=cvtpk(p2,p3); paA1.u[2]=cvtpk(p4,p5); paA1.u[3]=cvtpk(p6,p7); \
        p0=__builtin_amdgcn_exp2f(sB[0][0]); p1=__builtin_amdgcn_exp2f(sB[0][1]); \
        p2=__builtin_amdgcn_exp2f(sB[0][2]); p3=__builtin_amdgcn_exp2f(sB[0][3]); \
        p4=__builtin_amdgcn_exp2f(sB[1][0]); p5=__builtin_amdgcn_exp2f(sB[1][1]); \
        p6=__builtin_amdgcn_exp2f(sB[1][2]); p7=__builtin_amdgcn_exp2f(sB[1][3]); \
        lB += ((p0+p1)+(p2+p3)) + ((p4+p5)+(p6+p7)); \
        paB0.u[0]=cvtpk(p0,p1); paB0.u[1]=cvtpk(p2,p3); paB0.u[2]=cvtpk(p4,p5); paB0.u[3]=cvtpk(p6,p7); \
        p0=__builtin_amdgcn_exp2f(sB[2][0]); p1=__builtin_amdgcn_exp2f(sB[2][1]); \
        p2=__builtin_amdgcn_exp2f(sB[2][2]); p3=__builtin_amdgcn_exp2f(sB[2][3]); \
        p4=__builtin_amdgcn_exp2f(sB[3][0]); p5=__builtin_amdgcn_exp2f(sB[3][1]); \
        p6=__builtin_amdgcn_exp2f(sB[3][2]); p7=__builtin_amdgcn_exp2f(sB[3][3]); \
        lB += ((p0+p1)+(p2+p3)) + ((p4+p5)+(p6+p7)); \
        paB1.u[0]=cvtpk(p0,p1); paB1.u[1]=cvtpk(p2,p3); paB1.u[2]=cvtpk(p4,p5); paB1.u[3]=cvtpk(p6,p7); \
      } \
      __builtin_amdgcn_s_setprio(1); \
      { \
        bf16x8 v00 = *(const bf16x8*)((const char*)(VBC) + offV[0][0]); \
        bf16x8 v10 = *(const bf16x8*)((const char*)(VBC) + offV[1][0]); \
        bf16x8 v01 = *(const bf16x8*)((const char*)(VBC) + offV[0][1]); \
        bf16x8 v11 = *(const bf16x8*)((const char*)(VBC) + offV[1][1]); \
        oA0 = __builtin_amdgcn_mfma_f32_16x16x32_bf16(paA0.v, v00, oA0, 0,0,0); \
        oA1 = __builtin_amdgcn_mfma_f32_16x16x32_bf16(paA0.v, v10, oA1, 0,0,0); \
        oB0 = __builtin_amdgcn_mfma_f32_16x16x32_bf16(paB0.v, v00, oB0, 0,0,0); \
        oB1 = __builtin_amdgcn_mfma_f32_16x16x32_bf16(paB0.v, v10, oB1, 0,0,0); \
        oA0 = __builtin_amdgcn_mfma_f32_16x16x32_bf16(paA1.v, v01, oA0, 0,0,0); \
        oA1 = __builtin_amdgcn_mfma_f32_16x16x32_bf16(paA1.v, v11, oA1, 0,0,0); \
        oB0 = __builtin_amdgcn_mfma_f32_16x16x32_bf16(paB1.v, v01, oB0, 0,0,0); \
        oB1 = __builtin_amdgcn_mfma_f32_16x16x32_bf16(paB1.v, v11, oB1, 0,0,0); \
      } \
      __builtin_amdgcn_s_setprio(0); \
    } \
    __syncthreads(); \
  } while(0)

  const int nmax = (qt + 2) >> 1;
  const int jmax = (nmax + 1) >> 1;
  for (int j = 0; j < jmax; ++j){
    ABODY(2*j,   KB0, VB0, KB1, VB1);
    ABODY(2*j+1, KB1, VB1, KB0, VB0);
  }
  lA += __shfl_xor(lA, 16); lA += __shfl_xor(lA, 32);
  lB += __shfl_xor(lB, 16); lB += __shfl_xor(lB, 32);

  // ---- in-LDS merge of the two partial (unnormalized) results ----
  float* MO = (float*)SMEM;               // [64][34] padded
  float* ML = (float*)(SMEM + 12288);     // l[64]
  if (sg == 1){
    #pragma unroll
    for (int r=0;r<4;++r){
      int rowA = wvL*32 + 4*gq + r;
      MO[rowA*34 + lr]            = oA0[r];
      MO[rowA*34 + 16 + lr]       = oA1[r];
      MO[(rowA+16)*34 + lr]       = oB0[r];
      MO[(rowA+16)*34 + 16 + lr]  = oB1[r];
    }
    if (gq == 0){ ML[wvL*32 + lr] = lA; ML[wvL*32 + 16 + lr] = lB; }
  }
  __syncthreads();
  if (sg == 0){
    float lSA = lA + ML[wvL*32 + lr];
    float lSB = lB + ML[wvL*32 + 16 + lr];
    float lA_o[4], lB_o[4];
    #pragma unroll
    for (int r=0;r<4;++r){ lA_o[r] = __shfl(lSA, 4*gq + r); lB_o[r] = __shfl(lSB, 4*gq + r); }
    #pragma unroll
    for (int r=0;r<4;++r){
      int rowA = wvL*32 + 4*gq + r;
      float vA0 = (oA0[r] + MO[rowA*34 + lr])           / lA_o[r];
      float vA1 = (oA1[r] + MO[rowA*34 + 16 + lr])      / lA_o[r];
      float vB0 = (oB0[r] + MO[(rowA+16)*34 + lr])      / lB_o[r];
      float vB1 = (oB1[r] + MO[(rowA+16)*34 + 16 + lr]) / lB_o[r];
      size_t obA = (size_t)(b*2048 + q0 + rowA)*512 + h*32;
      Out[obA + lr]      = f2bf(vA0);
      Out[obA + 16 + lr] = f2bf(vA1);
      size_t obB = obA + (size_t)16*512;
      Out[obB + lr]      = f2bf(vB0);
      Out[obB + 16 + lr] = f2bf(vB1);
    }
  }
}

// ---------- workspace layout (bytes) ----------
#define WS_B2   0u                                   // 1536*4
#define WS_WT   8192u                                // 1536*1024*2 = 3145728
#define WS_W2T  (WS_WT + 3145728u)                   // 1024*512*2  = 1048576
#define WS_XB   (WS_W2T + 1048576u)                  // 4096*1024*2 = 8388608
#define WS_QKV  (WS_XB + 8388608u)                   // 4096*1536*2 = 12582912
#define WS_VT   (WS_QKV + 12582912u)                 // 1024*2048*2 = 4194304
#define WS_ATT  (WS_VT + 4194304u)                   // 4096*512*2  = 4194304
#define WS_WAB  (WS_ATT + 4194304u)                  // 1024*3072*2 = 6291456
#define WS_WPT  (WS_WAB + 6291456u)                  // 1024*1024*2 = 2097152
#define WS_MB   (WS_WPT + 2097152u)                  // 8192*2 = 16384

extern "C" void kernel_launch(void* const* d_in, const int* in_sizes, int n_in,
                              void* d_out, int out_size, void* d_ws, size_t ws_size,
                              hipStream_t stream) {
  const float* x  = (const float*)d_in[0];
  const float* Wa = (const float*)d_in[1];
  const float* ba = (const float*)d_in[2];
  const float* Wp = (const float*)d_in[3];
  const float* bp = (const float*)d_in[4];
  const float* kc = (const float*)d_in[5];
  const float* ke = (const float*)d_in[6];
  const float* vc = (const float*)d_in[7];
  const float* ve = (const float*)d_in[8];
  float* out = (float*)d_out;
  char* ws = (char*)d_ws;
  float* b2  = (float*)(ws + WS_B2);
  u16* Wt    = (u16*)(ws + WS_WT);
  u16* W2t   = (u16*)(ws + WS_W2T);
  u16* Xb    = (u16*)(ws + WS_XB);
  u16* QKVb  = (u16*)(ws + WS_QKV);
  u16* Vt    = (u16*)(ws + WS_VT);
  u16* Att   = (u16*)(ws + WS_ATT);
  u16* Wab   = (u16*)(ws + WS_WAB);
  u16* WpTb  = (u16*)(ws + WS_WPT);
  u16* Mb    = (u16*)(ws + WS_MB);

  convert_all<<<7428, 256, 0, stream>>>(x, Wa, ba, Wp, kc, ke, vc, ve, Xb, Wab, Mb, b2, WpTb);
  fold_gemms<<<dim3(16,64), 256, 0, stream>>>(Wab, Mb, WpTb, Wt, W2t);
  gemm64<u16><<<dim3(64,12), 256, 0, stream>>>(Xb, Wt, b2, QKVb, Vt, 4096, 1536, 1024, 1536);
  attn_fwd<<<dim3(32,32), 256, 0, stream>>>(QKVb, Vt, Att);
  gemm64<float><<<dim3(64,8), 256, 0, stream>>>(Att, W2t, bp, out, (u16*)nullptr, 4096, 1024, 512, 1024);
}